// Round 15
// baseline (274.109 us; speedup 1.0000x reference)
//
#include <hip/hip_runtime.h>
#include <cstdint>

#define FDIM 64
#define KNN 32
#define NBUCKET 256
#define MAXCAP 2048
#define SEG 8
#define OCAP 512
// band selection: keys from the MFMA filter are (d2_quant<<18)|p with d2_quant = floor(32*d2a),
// p < 2^18 (N=200000 < 262144). BANDQ = 96 -> 3.0 in d2 units; covers 2*eps for bf16 dot
// error eps up to ~1.45 (measured/typical eps ~0.1-0.3, 4-sigma bound ~0.6).
// R7: m ~= N*P(d2 < sample_q(32/S)+margin); S=12800 safe under MAXCAP.
// R8: filter time scales with m via the hit path.  R9: per-e __any branches regress.
// R10: hybrid seg layout (cnt[s][q], list[q][s]).  R11: d2s tiling neutral.
// R12: launch_bounds(256,8) caps unified VGPR+AGPR -> spill catastrophe.
// R13: single 16KB buffer + (256,4): best total (244.2us); filter ~76us is its floor.
// R14: cvt mega-kernel fusion REGRESSED total by ~25us (non-filter 168->194) despite
//   best-ever filter (75.3); finer buckets + ocnt fusion were fine.
// R15: A/B isolation: R13 launch structure + finer buckets + ocnt-in-thresh2 only.
#define BANDQ 96

typedef unsigned int u32;
typedef unsigned long long u64;
typedef __attribute__((ext_vector_type(8))) short bf16x8;
typedef __attribute__((ext_vector_type(4))) float f32x4;

// async global->LDS, 16B per lane. LDS dest is wave-uniform base + lane*16 (HW rule).
__device__ __forceinline__ void gload_lds16(const void* g, void* l) {
    __builtin_amdgcn_global_load_lds(
        (const __attribute__((address_space(1))) unsigned int*)g,
        (__attribute__((address_space(3))) unsigned int*)l,
        16, 0, 0);
}

// ---- shared fp32 helpers
__device__ __forceinline__ float load_query(const float* __restrict__ x, int q, float4* xv) {
    const float4* xp = (const float4*)(x + (size_t)q * FDIM);
    float n0 = 0.f, n1 = 0.f, n2 = 0.f, n3 = 0.f;
#pragma unroll
    for (int k = 0; k < 16; ++k) {
        float4 v = xp[k];
        xv[k] = v;
        n0 = fmaf(v.x, v.x, n0); n1 = fmaf(v.y, v.y, n1);
        n2 = fmaf(v.z, v.z, n2); n3 = fmaf(v.w, v.w, n3);
    }
    return (n0 + n1) + (n2 + n3);
}

__device__ __forceinline__ float dot_row(const float4* __restrict__ xv, const float* __restrict__ row) {
    const float4* rv = (const float4*)row;
    float d0 = 0.f, d1 = 0.f, d2 = 0.f, d3 = 0.f;
#pragma unroll
    for (int k = 0; k < 16; ++k) {
        float4 r = rv[k];
        float4 a = xv[k];
        d0 = fmaf(a.x, r.x, d0); d1 = fmaf(a.y, r.y, d1);
        d2 = fmaf(a.z, r.z, d2); d3 = fmaf(a.w, r.w, d3);
    }
    return (d0 + d1) + (d2 + d3);
}

// ---- K1: row norms (fallback path)
__global__ __launch_bounds__(256) void k_xnorm(const float* __restrict__ X, float* __restrict__ Xn, int N) {
    int i = blockIdx.x * 256 + threadIdx.x;
    if (i >= N) return;
    const float4* r = (const float4*)(X + (size_t)i * FDIM);
    float d0 = 0.f, d1 = 0.f, d2 = 0.f, d3 = 0.f;
#pragma unroll
    for (int k = 0; k < 16; ++k) {
        float4 v = r[k];
        d0 = fmaf(v.x, v.x, d0); d1 = fmaf(v.y, v.y, d1);
        d2 = fmaf(v.z, v.z, d2); d3 = fmaf(v.w, v.w, d3);
    }
    Xn[i] = (d0 + d1) + (d2 + d3);
}

// ---- K1b: fused fp32->bf16 (RNE) + transpose (no norm; fallback).
__global__ __launch_bounds__(256) void k_cvtT(const float* __restrict__ src, uint4* __restrict__ dst, int n_u4) {
    int i = blockIdx.x * 256 + threadIdx.x;
    if (i >= n_u4) return;
    int lane = i & 63;
    int kk = (i >> 6) & 1;
    int g = i >> 7;
    int row = g * 16 + (lane & 15);
    int col = kk * 32 + (lane >> 4) * 8;
    const float4* s = (const float4*)(src + (size_t)row * FDIM + col);
    float4 a = s[0], b = s[1];
    ushort o[8];
    const float* f = &a.x;
#pragma unroll
    for (int k = 0; k < 4; ++k) {
        u32 u = __float_as_uint(f[k]);
        o[k] = (ushort)((u + 0x7fffu + ((u >> 16) & 1u)) >> 16);
    }
    const float* gg = &b.x;
#pragma unroll
    for (int k = 0; k < 4; ++k) {
        u32 u = __float_as_uint(gg[k]);
        o[4 + k] = (ushort)((u + 0x7fffu + ((u >> 16) & 1u)) >> 16);
    }
    dst[i] = *(uint4*)o;
}

// ---- K1c: fused cvtT + row norms. Requires n_u4 % 256 == 0 (rows % 32 == 0).
__global__ __launch_bounds__(256) void k_cvtT_norm(const float* __restrict__ src, uint4* __restrict__ dst,
                                                   float* __restrict__ norms, int n_u4) {
    __shared__ float pn[4][16];
    int t = threadIdx.x;
    int i = blockIdx.x * 256 + t;
    int lane = t & 63;
    int w = t >> 6;
    int kk = (i >> 6) & 1;
    int g = i >> 7;
    int r = lane & 15;
    int row = g * 16 + r;
    int col = kk * 32 + (lane >> 4) * 8;
    const float4* s = (const float4*)(src + (size_t)row * FDIM + col);
    float4 a = s[0], b = s[1];
    float n0 = fmaf(a.x, a.x, a.y * a.y);
    float n1 = fmaf(a.z, a.z, a.w * a.w);
    float n2 = fmaf(b.x, b.x, b.y * b.y);
    float n3 = fmaf(b.z, b.z, b.w * b.w);
    float ss = (n0 + n1) + (n2 + n3);
    ushort o[8];
    const float* f = &a.x;
#pragma unroll
    for (int k = 0; k < 4; ++k) {
        u32 u = __float_as_uint(f[k]);
        o[k] = (ushort)((u + 0x7fffu + ((u >> 16) & 1u)) >> 16);
    }
    const float* gg = &b.x;
#pragma unroll
    for (int k = 0; k < 4; ++k) {
        u32 u = __float_as_uint(gg[k]);
        o[4 + k] = (ushort)((u + 0x7fffu + ((u >> 16) & 1u)) >> 16);
    }
    dst[i] = *(uint4*)o;
    ss += __shfl_xor(ss, 16);
    ss += __shfl_xor(ss, 32);
    if (lane < 16) pn[w][r] = ss;
    __syncthreads();
    if (t < 32) {
        float v = (t < 16) ? (pn[0][t] + pn[1][t]) : (pn[2][t - 16] + pn[3][t - 16]);
        norms[blockIdx.x * 32 + t] = v;
    }
}

// ---- legacy scalar sample-hist kernels (fallback when ws is tight) ----
__global__ __launch_bounds__(256) void k_hist(const float* __restrict__ x, const float* __restrict__ X,
                                              const float* __restrict__ Xn, u32* __restrict__ hist,
                                              int N, int nsamp, int sj) {
    __shared__ unsigned char h8[NBUCKET * 256];
    int t = threadIdx.x;
    u32* h32 = (u32*)h8;
#pragma unroll
    for (int k = 0; k < 64; ++k) h32[k * 256 + t] = 0;
    __syncthreads();
    int q = blockIdx.x * 256 + t;
    float4 xv[16];
    float xn = load_query(x, q, xv);
    for (int j = 0; j < sj; ++j) {
        int s = blockIdx.y * sj + j;
        int p = s * 16;
        if (s < nsamp && p < N) {
            float dp = dot_row(xv, X + (size_t)p * FDIM);
            float d2 = fmaxf(xn + Xn[p] - 2.f * dp, 0.f);
            int b = min(NBUCKET - 1, (int)d2);
            int idx = b * 256 + t;
            unsigned char v = h8[idx];
            h8[idx] = (v == 255u) ? v : (unsigned char)(v + 1);
        }
    }
    __syncthreads();
#pragma unroll
    for (int w = 0; w < 128; ++w) {
        u32 v0 = h8[(2 * w) * 256 + t];
        u32 v1 = h8[(2 * w + 1) * 256 + t];
        if (v0 | v1) atomicAdd(&hist[(size_t)q * 128 + w], v0 | (v1 << 16));
    }
}

__global__ __launch_bounds__(256) void k_thresh(const u32* __restrict__ hist, float* __restrict__ Tq, int B) {
    int q = blockIdx.x * 256 + threadIdx.x;
    if (q >= B) return;
    const u32* h = hist + (size_t)q * 128;
    int cum = 0;
    float T = (float)NBUCKET;
    for (int w = 0; w < 128; ++w) {
        u32 v = h[w];
        cum += (int)(v & 0xffffu);
        if (cum >= KNN) { T = (float)(2 * w + 1); break; }
        cum += (int)(v >> 16);
        if (cum >= KNN) { T = (float)(2 * w + 2); break; }
    }
    Tq[q] = T + 2.0f;
}

// ---- K2 (MFMA sample pass): 0.5-wide d2a buckets for the first S rows.
// d2s TILED layout [tile][q][p_local]: each block writes one contiguous 16KB span.
__global__ __launch_bounds__(256, 3) void k_sample_d2(
        const uint4* __restrict__ xT, const uint4* __restrict__ XT,
        const float* __restrict__ qn, const float* __restrict__ Xn,
        unsigned char* __restrict__ d2s, int S) {
    int t = threadIdx.x;
    int w = t >> 6, lane = t & 63;
    int G = lane >> 4, r = lane & 15;
    int qg = blockIdx.x;
    int wq = qg * 128 + w * 32;
    int pb = blockIdx.y * 128;
    int Bq = gridDim.x * 128;   // total queries

    bf16x8 afr[2][2];
#pragma unroll
    for (int kk = 0; kk < 2; ++kk)
#pragma unroll
        for (int mi = 0; mi < 2; ++mi) {
            uint4 v = xT[(size_t)(((wq >> 4) + mi) * 2 + kk) * 64 + lane];
            afr[kk][mi] = *(bf16x8*)&v;
        }
    float qr[8];
#pragma unroll
    for (int e = 0; e < 8; ++e)
        qr[e] = qn[wq + (e >> 2) * 16 + G * 4 + (e & 3)];

    unsigned char* dtile = d2s + (size_t)blockIdx.y * Bq * 128;

#pragma unroll
    for (int half = 0; half < 2; ++half) {
        int nb = half * 4;
        bf16x8 bfr[4][2];
#pragma unroll
        for (int j = 0; j < 4; ++j) {
            int gp = (pb >> 4) + nb + j;
#pragma unroll
            for (int kk = 0; kk < 2; ++kk) {
                uint4 v = XT[(size_t)(gp * 2 + kk) * 64 + lane];
                bfr[j][kk] = *(bf16x8*)&v;
            }
        }
        float xnv[4];
#pragma unroll
        for (int j = 0; j < 4; ++j) xnv[j] = Xn[pb + (nb + j) * 16 + r];

        f32x4 acc[2][4];
#pragma unroll
        for (int mi = 0; mi < 2; ++mi)
#pragma unroll
            for (int j = 0; j < 4; ++j) acc[mi][j] = (f32x4){0.f, 0.f, 0.f, 0.f};
#pragma unroll
        for (int kk = 0; kk < 2; ++kk)
#pragma unroll
            for (int j = 0; j < 4; ++j) {
                acc[0][j] = __builtin_amdgcn_mfma_f32_16x16x32_bf16(afr[kk][0], bfr[j][kk], acc[0][j], 0, 0, 0);
                acc[1][j] = __builtin_amdgcn_mfma_f32_16x16x32_bf16(afr[kk][1], bfr[j][kk], acc[1][j], 0, 0, 0);
            }
#pragma unroll
        for (int j = 0; j < 4; ++j) {
            int pl = (nb + j) * 16 + r;   // p within tile, 0..127
            float xnp = xnv[j];
#pragma unroll
            for (int e = 0; e < 8; ++e) {
                float d2a = qr[e] + fmaf(-2.f, acc[e >> 2][j][e & 3], xnp);
                int b = (int)(d2a * 2.0f);   // 0.5-wide buckets (threshold region d2~46 << 127.5)
                b = b < 0 ? 0 : (b > 255 ? 255 : b);
                int q = wq + (e >> 2) * 16 + G * 4 + (e & 3);
                dtile[(size_t)q * 128 + pl] = (unsigned char)b;
            }
        }
    }
}

// ---- K2b: per-query hist of 0.5-wide d2a buckets -> T = (b+1)/2 + 2.
// Also zeroes ocnt[q] (replaces the ocnt memset; runs before the filter).
__global__ __launch_bounds__(256) void k_thresh2(const unsigned char* __restrict__ d2s,
                                                 float* __restrict__ Tq, u32* __restrict__ ocnt, int S) {
    __shared__ u32 h[4][NBUCKET];
    int t = threadIdx.x;
    int w = t >> 6;
    int q = blockIdx.x;
    int Bq = gridDim.x;
    if (t == 0) ocnt[q] = 0;
#pragma unroll
    for (int k = 0; k < 4; ++k) h[k][t] = 0;
    __syncthreads();
    const u32* base32 = (const u32*)d2s;
    int n32 = S >> 2;   // Stiles*32 u32 words per query
    for (int i = t; i < n32; i += 256) {
        int tile = i >> 5, c = i & 31;
        u32 v = base32[((size_t)tile * Bq + q) * 32 + c];
        u32* hw = h[w];
        atomicAdd(&hw[v & 255u], 1u);
        atomicAdd(&hw[(v >> 8) & 255u], 1u);
        atomicAdd(&hw[(v >> 16) & 255u], 1u);
        atomicAdd(&hw[v >> 24], 1u);
    }
    __syncthreads();
    u32 s = h[0][t] + h[1][t] + h[2][t] + h[3][t];
    h[0][t] = s;
    __syncthreads();
    if (t == 0) {
        int cum = 0;
        float T = 128.0f;
        for (int b = 0; b < NBUCKET; ++b) {
            cum += (int)h[0][b];
            if (cum >= KNN) { T = 0.5f * (float)(b + 1); break; }
        }
        Tq[q] = T + 2.0f;
    }
}

// ---- K3: MFMA filter, single 16KB LDS buffer, launch_bounds(256,4) (R13 config, best).
__global__ __launch_bounds__(256, 4) void k_mfma_filter(
        const uint4* __restrict__ xT, const uint4* __restrict__ XT,
        const float* __restrict__ qn, const float* __restrict__ Xn,
        const float* __restrict__ Tf,
        u32* __restrict__ cnt_seg, u32* __restrict__ list_seg,
        u32* __restrict__ ocnt, u32* __restrict__ olist,
        int N, int nStripsPad, int strip, int B) {
    __shared__ uint4 sbuf[1024];   // one 16 KB tile buffer
    __shared__ u32 ldsCnt[128];

    int t = threadIdx.x;
    int w = t >> 6, lane = t & 63;
    int G = lane >> 4, r = lane & 15;

    int bid = blockIdx.x;
    int qg = (bid >> 3) & 7;
    int sIdx = (bid & 7) | ((bid >> 6) << 3);
    int qbase = qg * 128;
    int wq = qbase + w * 32;

    if (t < 128) ldsCnt[t] = 0;

    bf16x8 afr[2][2];
#pragma unroll
    for (int kk = 0; kk < 2; ++kk)
#pragma unroll
        for (int mi = 0; mi < 2; ++mi) {
            uint4 v = xT[(size_t)(((wq >> 4) + mi) * 2 + kk) * 64 + lane];
            afr[kk][mi] = *(bf16x8*)&v;
        }
    float nT[8], qnr[8];
#pragma unroll
    for (int e = 0; e < 8; ++e) {
        int rl = wq + (e >> 2) * 16 + G * 4 + (e & 3);
        float qv = qn[rl];
        qnr[e] = qv;
        nT[e] = -0.5f * (Tf[rl] - qv);   // pass iff acc > nT[e]
    }

    // list in [q][s] layout: per-q contiguous row for k_final
    u32* segBase = list_seg + ((size_t)qbase * nStripsPad + (size_t)sIdx) * SEG;

    int pb0 = sIdx * strip * 128;
    int ntl = (pb0 < N) ? strip : 0;   // whole-strip padding blocks skip compute

    for (int s = 0; s < ntl; ++s) {
        int pb = pb0 + s * 128;
        // stage tile s (all waves cooperate; 16 KB contiguous)
        {
            const char* src = (const char*)XT + (size_t)(pb >> 4) * 2048 + w * 1024 + lane * 16;
            char* dst = (char*)&sbuf[0] + w * 1024;
            gload_lds16(src, dst);
            gload_lds16(src + 4096, dst + 4096);
            gload_lds16(src + 8192, dst + 8192);
            gload_lds16(src + 12288, dst + 12288);
        }
        __syncthreads();   // drains vmcnt -> staged data visible
        const uint4* cur = &sbuf[0];

#pragma unroll
        for (int half = 0; half < 2; ++half) {
            int nb = half * 4;
            bf16x8 bfr[4][2];
#pragma unroll
            for (int j = 0; j < 4; ++j) {
#pragma unroll
                for (int kk = 0; kk < 2; ++kk) {
                    uint4 v = cur[((nb + j) * 2 + kk) * 64 + lane];
                    bfr[j][kk] = *(bf16x8*)&v;
                }
            }
            float xnv[4], ai[4];
#pragma unroll
            for (int j = 0; j < 4; ++j) {
                xnv[j] = Xn[pb + (nb + j) * 16 + r];
                ai[j] = -0.5f * xnv[j];
            }

            f32x4 acc[2][4];
#pragma unroll
            for (int mi = 0; mi < 2; ++mi)
#pragma unroll
                for (int j = 0; j < 4; ++j) acc[mi][j] = (f32x4){ai[j], ai[j], ai[j], ai[j]};
#pragma unroll
            for (int kk = 0; kk < 2; ++kk)
#pragma unroll
                for (int j = 0; j < 4; ++j) {
                    acc[0][j] = __builtin_amdgcn_mfma_f32_16x16x32_bf16(afr[kk][0], bfr[j][kk], acc[0][j], 0, 0, 0);
                    acc[1][j] = __builtin_amdgcn_mfma_f32_16x16x32_bf16(afr[kk][1], bfr[j][kk], acc[1][j], 0, 0, 0);
                }
#pragma unroll
            for (int j = 0; j < 4; ++j) {
                int p = pb + (nb + j) * 16 + r;
                bool ce[8];
#pragma unroll
                for (int e = 0; e < 8; ++e)
                    ce[e] = acc[e >> 2][j][e & 3] > nT[e];
                if ((ce[0] | ce[1] | ce[2] | ce[3] | ce[4] | ce[5] | ce[6] | ce[7]) && p < N) {
#pragma unroll
                    for (int e = 0; e < 8; ++e) {
                        if (ce[e]) {
                            float d2a = fmaf(-2.f, acc[e >> 2][j][e & 3], qnr[e]);
                            d2a = d2a < 0.f ? 0.f : d2a;
                            u32 dq = (u32)(d2a * 32.f);
                            if (dq > 16383u) dq = 16383u;
                            u32 key = (dq << 18) | (u32)p;
                            int ql = w * 32 + (e >> 2) * 16 + G * 4 + (e & 3);
                            u32 slot = atomicAdd(&ldsCnt[ql], 1u);
                            if (slot < SEG) {
                                segBase[(size_t)ql * nStripsPad * SEG + slot] = key;
                            } else {
                                u32 gs = atomicAdd(&ocnt[qbase + ql], 1u);
                                if (gs < OCAP) olist[(size_t)(qbase + ql) * OCAP + gs] = key;
                            }
                        }
                    }
                }
            }
        }
        __syncthreads();   // all waves done with sbuf before next stage overwrites
    }

    if (ntl == 0) __syncthreads();   // uniform per block; aligns no-work blocks
    if (t < 128) cnt_seg[(size_t)sIdx * B + qbase + t] = min(ldsCnt[t], (u32)SEG);
}

// ---- K3 (scalar fallback, flat list + global atomics)
__global__ __launch_bounds__(256) void k_filter_scalar(const float* __restrict__ x, const float* __restrict__ X,
                                                       const float* __restrict__ Xn, const float* __restrict__ Tq,
                                                       u32* __restrict__ cnt, u32* __restrict__ list,
                                                       int N, int cap) {
    int t = threadIdx.x;
    int q = blockIdx.x * 256 + t;
    float4 xv[16];
    float xn = load_query(x, q, xv);
    float T = Tq[q];
    int base = blockIdx.y * 1024;
    int lim = min(1024, N - base);
    for (int j = 0; j < lim; ++j) {
        int p = base + j;
        float dp = dot_row(xv, X + (size_t)p * FDIM);
        float d2 = fmaxf(xn + Xn[p] - 2.f * dp, 0.f);
        if (d2 < T) {
            u32 slot = atomicAdd(&cnt[q], 1u);
            if (slot < (u32)cap) list[(size_t)q * cap + slot] = (u32)p;
        }
    }
}

// ---- K4: gather + band-select on approx d2 + pipelined exact rescore of the band only
//          + wave-0 butterfly top-32 + NN head
__global__ __launch_bounds__(256) void k_final(const float* __restrict__ x, const float* __restrict__ X,
                                               const float* __restrict__ y, const float* __restrict__ Xn,
                                               const float* __restrict__ Wg, const float* __restrict__ bg,
                                               const float* __restrict__ W1, const float* __restrict__ b1,
                                               const float* __restrict__ Wl, const float* __restrict__ bl,
                                               const u32* __restrict__ cnt_seg, const u32* __restrict__ list_seg,
                                               const u32* __restrict__ ocnt, const u32* __restrict__ olist,
                                               const u32* __restrict__ cnt_flat, const u32* __restrict__ list_flat,
                                               float* __restrict__ out, int nStripsPad, int cap_flat, int flat,
                                               int N, int B) {
    __shared__ u64 keys[MAXCAP];
    __shared__ u32 nsh;
    __shared__ u64 wk[4];
    __shared__ int wp[4];
    __shared__ u32 sel[KNN];
    __shared__ float gkc[KNN * 16];
    __shared__ float aggc[16];
    __shared__ float red[128];
    __shared__ u32 hist[2048];   // approx-d2 histogram; reused as band candidate list
    __shared__ u32 wtot[4];
    __shared__ u32 cutq_sh;
    __shared__ u32 nrs;

    int t = threadIdx.x;
    int w = t >> 6, lane = t & 63;
    int q = blockIdx.x;
    int m;

    if (flat) {
        m = (int)min(cnt_flat[q], (u32)cap_flat);
        const u32* lq = list_flat + (size_t)q * cap_flat;
        for (int i = t; i < m; i += 256) keys[i] = lq[i];
    } else {
        if (t == 0) nsh = 0;
        __syncthreads();
        for (int seg = t; seg < nStripsPad; seg += 256) {
            u32 c = cnt_seg[(size_t)seg * B + q];
            if (c) {
                u32 base = atomicAdd(&nsh, c);
                const u32* sp = list_seg + ((size_t)q * nStripsPad + seg) * SEG;
                for (u32 j = 0; j < c; ++j) {
                    u32 idx = base + j;
                    if (idx < MAXCAP) keys[idx] = sp[j];
                }
            }
        }
        __syncthreads();
        int m0 = (int)min(nsh, (u32)MAXCAP);
        int oc = (int)min(ocnt[q], (u32)OCAP);
        for (int i = t; i < oc; i += 256)
            if (m0 + i < MAXCAP) keys[m0 + i] = olist[(size_t)q * OCAP + i];
        m = min(m0 + oc, MAXCAP);
    }
    __syncthreads();

    // ---- Phase A: find approx 32nd-smallest d2 (quantized) and set the rescore cutoff.
    if (!flat) {
        for (int i = t; i < 2048; i += 256) hist[i] = 0;
        if (t == 0) cutq_sh = 0xFFFFFFFFu;
        __syncthreads();
        for (int i = t; i < m; i += 256) atomicAdd(&hist[((u32)keys[i]) >> 21], 1u);
        __syncthreads();
        u32 s = 0;
#pragma unroll
        for (int j = 0; j < 8; ++j) s += hist[t * 8 + j];
        u32 run = s;
#pragma unroll
        for (int off = 1; off < 64; off <<= 1) {
            u32 v = __shfl_up(run, off);
            if (lane >= off) run += v;
        }
        if (lane == 63) wtot[w] = run;
        __syncthreads();
        u32 wo = 0;
#pragma unroll
        for (int v = 0; v < 4; ++v) wo += (v < w) ? wtot[v] : 0u;
        u32 inc = wo + run;
        u32 exc = inc - s;
        if (exc < (u32)KNN && inc >= (u32)KNN) {
            u32 cum = exc;
#pragma unroll
            for (int j = 0; j < 8; ++j) {
                cum += hist[t * 8 + j];
                if (cum >= (u32)KNN) { cutq_sh = (u32)(((t * 8 + j + 1) << 3) + BANDQ); break; }
            }
        }
    }
    if (t == 0) nrs = 0;
    __syncthreads();
    u32 cutq = flat ? 0xFFFFFFFFu : cutq_sh;

    // ---- compact the band into cand[] (reuse hist storage)
    u32* cand = hist;
    for (int i = t; i < m; i += 256) {
        u32 k = (u32)keys[i];
        if ((k >> 18) <= cutq) cand[atomicAdd(&nrs, 1u)] = k & 0x3FFFFu;
    }
    __syncthreads();
    int mr = (int)min(nrs, (u32)MAXCAP);

    // ---- coalesced exact fp32 rescore of the band with 8-deep load pipeline.
    {
        int ch = lane & 15;
        int rsub = lane >> 4;  // 0..3
        float4 xq4 = ((const float4*)(x + (size_t)q * FDIM))[ch];
        float xs = fmaf(xq4.x, xq4.x, fmaf(xq4.y, xq4.y, fmaf(xq4.z, xq4.z, xq4.w * xq4.w)));
        xs += __shfl_xor(xs, 1);
        xs += __shfl_xor(xs, 2);
        xs += __shfl_xor(xs, 4);
        xs += __shfl_xor(xs, 8);
        float xn = xs;
        for (int base = w * 32; base < mr; base += 128) {
            int ri[8]; u32 pp[8]; bool val[8]; float4 vv[8];
#pragma unroll
            for (int u = 0; u < 8; ++u) {
                ri[u] = base + u * 4 + rsub;
                val[u] = ri[u] < mr;
                pp[u] = val[u] ? cand[ri[u]] : 0u;
            }
#pragma unroll
            for (int u = 0; u < 8; ++u)
                vv[u] = ((const float4*)(X + (size_t)pp[u] * FDIM))[ch];
#pragma unroll
            for (int u = 0; u < 8; ++u) {
                float part = fmaf(xq4.x, vv[u].x, fmaf(xq4.y, vv[u].y, fmaf(xq4.z, vv[u].z, xq4.w * vv[u].w)));
                part += __shfl_xor(part, 1);
                part += __shfl_xor(part, 2);
                part += __shfl_xor(part, 4);
                part += __shfl_xor(part, 8);
                if (val[u] && ch == 0) {
                    float d2 = fmaxf(xn + Xn[pp[u]] - 2.f * part, 0.f);
                    keys[ri[u]] = ((u64)__float_as_uint(d2) << 32) | pp[u];
                }
            }
        }
    }
    __syncthreads();

    if (mr <= 512) {
        if (w == 0) {
            u64 rk[8];
#pragma unroll
            for (int i = 0; i < 8; ++i) {
                int idx = lane + (i << 6);
                rk[i] = (idx < mr) ? keys[idx] : ~0ull;
            }
            for (int r = 0; r < KNN; ++r) {
                u64 bk = ~0ull;
                int bs = 0;
#pragma unroll
                for (int i = 0; i < 8; ++i)
                    if (rk[i] < bk) { bk = rk[i]; bs = i; }
                int bo = lane;
#pragma unroll
                for (int off = 1; off < 64; off <<= 1) {
                    u64 ok = __shfl_xor(bk, off);
                    int oo = __shfl_xor(bo, off);
                    if (ok < bk) { bk = ok; bo = oo; }
                }
                if (lane == bo) rk[bs] = ~0ull;
                if (lane == 0) sel[r] = (u32)bk;
            }
        }
        __syncthreads();
    } else {
        for (int r = 0; r < KNN; ++r) {
            u64 bk = ~0ull;
            int bp = -1;
            for (int i = t; i < mr; i += 256) {
                u64 k = keys[i];
                if (k < bk) { bk = k; bp = i; }
            }
#pragma unroll
            for (int off = 32; off > 0; off >>= 1) {
                u64 ok = __shfl_down(bk, off);
                int op = __shfl_down(bp, off);
                if (ok < bk) { bk = ok; bp = op; }
            }
            if (lane == 0) { wk[w] = bk; wp[w] = bp; }
            __syncthreads();
            if (t == 0) {
                u64 fb = wk[0];
                int fp = wp[0];
                for (int v = 1; v < 4; ++v)
                    if (wk[v] < fb) { fb = wk[v]; fp = wp[v]; }
                sel[r] = (u32)(fb & 0xffffffffu);
                if (fp >= 0) keys[fp] = ~0ull;
            }
            __syncthreads();
        }
    }

    int c = t & 15, kk = t >> 4;
#pragma unroll
    for (int rep = 0; rep < 2; ++rep) {
        int k = kk + 16 * rep;
        int nb = min((int)sel[k], N - 1);
        const float* Xr = X + (size_t)nb * FDIM;
        float acc = bg[c];
#pragma unroll
        for (int f = 0; f < FDIM; ++f) acc = fmaf(Xr[f], Wg[f * 16 + c], acc);
        acc = fmaf(y[nb], Wg[FDIM * 16 + c], acc);
        gkc[k * 16 + c] = tanhf(acc);
    }
    __syncthreads();
    if (t < 16) {
        float s = 0.f;
#pragma unroll
        for (int k = 0; k < KNN; ++k) s += gkc[k * 16 + t];
        aggc[t] = s;
    }
    __syncthreads();
    if (t < 128) {
        const float* xq = x + (size_t)q * FDIM;
        float acc = b1[t];
#pragma unroll
        for (int f = 0; f < FDIM; ++f) acc = fmaf(xq[f], W1[f * 128 + t], acc);
#pragma unroll
        for (int cc2 = 0; cc2 < 16; ++cc2) acc = fmaf(aggc[cc2], W1[(FDIM + cc2) * 128 + t], acc);
        red[t] = tanhf(acc) * Wl[t];
    }
    __syncthreads();
    for (int off = 64; off > 0; off >>= 1) {
        if (t < off) red[t] += red[t + off];
        __syncthreads();
    }
    if (t == 0) out[q] = 1.f / (1.f + expf(-(red[0] + bl[0])));
}

extern "C" void kernel_launch(void* const* d_in, const int* in_sizes, int n_in,
                              void* d_out, int out_size, void* d_ws, size_t ws_size,
                              hipStream_t stream) {
    const float* x  = (const float*)d_in[0];
    const float* X  = (const float*)d_in[1];
    const float* y  = (const float*)d_in[2];
    const float* Wg = (const float*)d_in[3];
    const float* bg = (const float*)d_in[4];
    const float* W1 = (const float*)d_in[5];
    const float* b1 = (const float*)d_in[6];
    const float* Wl = (const float*)d_in[7];
    const float* bl = (const float*)d_in[8];
    float* out = (float*)d_out;

    int B = in_sizes[0] / FDIM;  // 1024
    int N = in_sizes[1] / FDIM;  // 200000

    const int strip = 4;
    int nTiles = (N + 127) / 128;
    int nStrips = (nTiles + strip - 1) / strip;
    nStrips = (nStrips + 7) & ~7;
    int nStripsPad = nStrips;           // 392
    int Npad = nStrips * strip * 128;   // 200704

    char* w = (char*)d_ws;
    size_t off = 0;
    auto alloc = [&](size_t bytes) { void* p = w + off; off += (bytes + 255) & ~(size_t)255; return p; };
    float* Xn  = (float*)alloc((size_t)Npad * 4);
    float* qn  = (float*)alloc((size_t)B * 4);
    u32* hist  = (u32*)alloc((size_t)B * 512);
    float* Tq  = (float*)alloc((size_t)B * 4);
    u32* cnt   = (u32*)alloc((size_t)B * 4);

    size_t xTB = (size_t)B * 128;
    size_t XTB = (size_t)(Npad / 16) * 2048;
    size_t segCntB = (size_t)B * nStripsPad * 4;
    size_t segListB = (size_t)B * nStripsPad * SEG * 4;
    size_t ocntB = (size_t)B * 4;
    size_t olistB = (size_t)B * OCAP * 4;
    size_t rem = (ws_size > off) ? ws_size - off : 0;
    bool mfma_path = rem >= xTB + XTB + segCntB + segListB + ocntB + olistB + 4096;

    uint4* xT = nullptr; uint4* XT = nullptr;
    u32 *cnt_seg = nullptr, *list_seg = nullptr, *ocnt = nullptr, *olist = nullptr;
    u32* list_flat = nullptr; unsigned char* d2s = nullptr;
    int cap_flat = 64, Stiles = 0;
    if (mfma_path) {
        xT = (uint4*)alloc(xTB);
        XT = (uint4*)alloc(XTB);
        cnt_seg  = (u32*)alloc(segCntB);
        list_seg = (u32*)alloc(segListB);
        ocnt     = (u32*)alloc(ocntB);
        olist    = (u32*)alloc(olistB);
        rem = (ws_size > off) ? ws_size - off : 0;
        size_t st = rem / ((size_t)B * 128);
        Stiles = st > 100 ? 100 : (int)st;
        int maxFull = N / 128;
        if (Stiles > maxFull) Stiles = maxFull;
        if (Stiles >= 96) d2s = (unsigned char*)alloc((size_t)Stiles * 128 * B);
        else Stiles = 0;
    } else {
        size_t c = rem / ((size_t)B * 4);
        cap_flat = c > MAXCAP ? MAXCAP : (int)c;
        if (cap_flat < 64) cap_flat = 64;
        list_flat = (u32*)alloc((size_t)B * cap_flat * 4);
    }

    if (mfma_path) {
        hipMemsetAsync(Xn + N, 0, (size_t)(Npad - N) * 4, stream);
        size_t realXT = (size_t)(N / 16) * 2048;
        hipMemsetAsync((char*)XT + realXT, 0, XTB - realXT, stream);

        int nxu4 = B * 8, nXu4 = N * 8;
        if ((nxu4 & 255) == 0) {
            k_cvtT_norm<<<dim3(nxu4 / 256), 256, 0, stream>>>(x, xT, qn, nxu4);
        } else {
            k_xnorm<<<dim3((B + 255) / 256), 256, 0, stream>>>(x, qn, B);
            k_cvtT<<<dim3((nxu4 + 255) / 256), 256, 0, stream>>>(x, xT, nxu4);
        }
        if ((nXu4 & 255) == 0) {
            k_cvtT_norm<<<dim3(nXu4 / 256), 256, 0, stream>>>(X, XT, Xn, nXu4);
        } else {
            k_xnorm<<<dim3((N + 255) / 256), 256, 0, stream>>>(X, Xn, N);
            k_cvtT<<<dim3((nXu4 + 255) / 256), 256, 0, stream>>>(X, XT, nXu4);
        }

        if (Stiles > 0) {
            int S = Stiles * 128;
            k_sample_d2<<<dim3(8, Stiles), 256, 0, stream>>>(xT, XT, qn, Xn, d2s, S);
            k_thresh2<<<dim3(B), 256, 0, stream>>>(d2s, Tq, ocnt, S);
        } else {
            hipMemsetAsync(ocnt, 0, ocntB, stream);
            hipMemsetAsync(hist, 0, (size_t)B * 512, stream);
            int nsamp = (N + 15) / 16;
            int chunks = 128;
            int sj = (nsamp + chunks - 1) / chunks;
            k_hist<<<dim3(B / 256, chunks), 256, 0, stream>>>(x, X, Xn, hist, N, nsamp, sj);
            k_thresh<<<dim3((B + 255) / 256), 256, 0, stream>>>(hist, Tq, B);
        }

        k_mfma_filter<<<dim3(8 * nStrips), 256, 0, stream>>>(
            xT, XT, qn, Xn, Tq, cnt_seg, list_seg, ocnt, olist, N, nStripsPad, strip, B);

        k_final<<<dim3(B), 256, 0, stream>>>(x, X, y, Xn, Wg, bg, W1, b1, Wl, bl,
                                             cnt_seg, list_seg, ocnt, olist,
                                             nullptr, nullptr, out, nStripsPad, 0, 0, N, B);
    } else {
        k_xnorm<<<dim3((N + 255) / 256), 256, 0, stream>>>(X, Xn, N);
        k_xnorm<<<dim3((B + 255) / 256), 256, 0, stream>>>(x, qn, B);
        hipMemsetAsync(cnt, 0, (size_t)B * 4, stream);
        hipMemsetAsync(hist, 0, (size_t)B * 512, stream);
        int nsamp = (N + 15) / 16;
        int chunks = 128;
        int sj = (nsamp + chunks - 1) / chunks;
        k_hist<<<dim3(B / 256, chunks), 256, 0, stream>>>(x, X, Xn, hist, N, nsamp, sj);
        k_thresh<<<dim3((B + 255) / 256), 256, 0, stream>>>(hist, Tq, B);
        k_filter_scalar<<<dim3(B / 256, (N + 1023) / 1024), 256, 0, stream>>>(
            x, X, Xn, Tq, cnt, list_flat, N, cap_flat);
        k_final<<<dim3(B), 256, 0, stream>>>(x, X, y, Xn, Wg, bg, W1, b1, Wl, bl,
                                             nullptr, nullptr, nullptr, nullptr,
                                             cnt, list_flat, out, nStripsPad, cap_flat, 1, N, B);
    }
}

// Round 16
// 244.838 us; speedup vs baseline: 1.1196x; 1.1196x over previous
//
#include <hip/hip_runtime.h>
#include <cstdint>

#define FDIM 64
#define KNN 32
#define NBUCKET 256
#define MAXCAP 2048
#define SEG 8
#define OCAP 512
// band selection: keys from the MFMA filter are (d2_quant<<18)|p with d2_quant = floor(32*d2a),
// p < 2^18 (N=200000 < 262144). BANDQ = 96 -> 3.0 in d2 units; covers 2*eps for bf16 dot
// error eps up to ~1.45 (measured/typical eps ~0.1-0.3, 4-sigma bound ~0.6).
// R7: m ~= N*P(d2 < sample_q(32/S)+margin); S=12800 safe under MAXCAP.
// R8: filter time scales with m via the hit path.  R9: per-e __any branches regress.
// R10: hybrid seg layout (cnt[s][q], list[q][s]).  R11: d2s tiling neutral.
// R12: launch_bounds(256,8) caps unified VGPR+AGPR -> spill catastrophe.
// R13: single 16KB buffer + (256,4): best total (244.2us).
// R14/R15 LESSON: 0.5-wide sample buckets saturate ~50% of Gaussian d2 (mean 2F=128)
//   into bucket 255 -> ~6400 same-address LDS atomics/block in thresh2 -> ~25us
//   regression. REVERTED to 1-wide buckets. ocnt-in-thresh2 fusion kept (trivial).
#define BANDQ 96

typedef unsigned int u32;
typedef unsigned long long u64;
typedef __attribute__((ext_vector_type(8))) short bf16x8;
typedef __attribute__((ext_vector_type(4))) float f32x4;

// async global->LDS, 16B per lane. LDS dest is wave-uniform base + lane*16 (HW rule).
__device__ __forceinline__ void gload_lds16(const void* g, void* l) {
    __builtin_amdgcn_global_load_lds(
        (const __attribute__((address_space(1))) unsigned int*)g,
        (__attribute__((address_space(3))) unsigned int*)l,
        16, 0, 0);
}

// ---- shared fp32 helpers
__device__ __forceinline__ float load_query(const float* __restrict__ x, int q, float4* xv) {
    const float4* xp = (const float4*)(x + (size_t)q * FDIM);
    float n0 = 0.f, n1 = 0.f, n2 = 0.f, n3 = 0.f;
#pragma unroll
    for (int k = 0; k < 16; ++k) {
        float4 v = xp[k];
        xv[k] = v;
        n0 = fmaf(v.x, v.x, n0); n1 = fmaf(v.y, v.y, n1);
        n2 = fmaf(v.z, v.z, n2); n3 = fmaf(v.w, v.w, n3);
    }
    return (n0 + n1) + (n2 + n3);
}

__device__ __forceinline__ float dot_row(const float4* __restrict__ xv, const float* __restrict__ row) {
    const float4* rv = (const float4*)row;
    float d0 = 0.f, d1 = 0.f, d2 = 0.f, d3 = 0.f;
#pragma unroll
    for (int k = 0; k < 16; ++k) {
        float4 r = rv[k];
        float4 a = xv[k];
        d0 = fmaf(a.x, r.x, d0); d1 = fmaf(a.y, r.y, d1);
        d2 = fmaf(a.z, r.z, d2); d3 = fmaf(a.w, r.w, d3);
    }
    return (d0 + d1) + (d2 + d3);
}

// ---- K1: row norms (fallback path)
__global__ __launch_bounds__(256) void k_xnorm(const float* __restrict__ X, float* __restrict__ Xn, int N) {
    int i = blockIdx.x * 256 + threadIdx.x;
    if (i >= N) return;
    const float4* r = (const float4*)(X + (size_t)i * FDIM);
    float d0 = 0.f, d1 = 0.f, d2 = 0.f, d3 = 0.f;
#pragma unroll
    for (int k = 0; k < 16; ++k) {
        float4 v = r[k];
        d0 = fmaf(v.x, v.x, d0); d1 = fmaf(v.y, v.y, d1);
        d2 = fmaf(v.z, v.z, d2); d3 = fmaf(v.w, v.w, d3);
    }
    Xn[i] = (d0 + d1) + (d2 + d3);
}

// ---- K1b: fused fp32->bf16 (RNE) + transpose (no norm; fallback).
__global__ __launch_bounds__(256) void k_cvtT(const float* __restrict__ src, uint4* __restrict__ dst, int n_u4) {
    int i = blockIdx.x * 256 + threadIdx.x;
    if (i >= n_u4) return;
    int lane = i & 63;
    int kk = (i >> 6) & 1;
    int g = i >> 7;
    int row = g * 16 + (lane & 15);
    int col = kk * 32 + (lane >> 4) * 8;
    const float4* s = (const float4*)(src + (size_t)row * FDIM + col);
    float4 a = s[0], b = s[1];
    ushort o[8];
    const float* f = &a.x;
#pragma unroll
    for (int k = 0; k < 4; ++k) {
        u32 u = __float_as_uint(f[k]);
        o[k] = (ushort)((u + 0x7fffu + ((u >> 16) & 1u)) >> 16);
    }
    const float* gg = &b.x;
#pragma unroll
    for (int k = 0; k < 4; ++k) {
        u32 u = __float_as_uint(gg[k]);
        o[4 + k] = (ushort)((u + 0x7fffu + ((u >> 16) & 1u)) >> 16);
    }
    dst[i] = *(uint4*)o;
}

// ---- K1c: fused cvtT + row norms. Requires n_u4 % 256 == 0 (rows % 32 == 0).
__global__ __launch_bounds__(256) void k_cvtT_norm(const float* __restrict__ src, uint4* __restrict__ dst,
                                                   float* __restrict__ norms, int n_u4) {
    __shared__ float pn[4][16];
    int t = threadIdx.x;
    int i = blockIdx.x * 256 + t;
    int lane = t & 63;
    int w = t >> 6;
    int kk = (i >> 6) & 1;
    int g = i >> 7;
    int r = lane & 15;
    int row = g * 16 + r;
    int col = kk * 32 + (lane >> 4) * 8;
    const float4* s = (const float4*)(src + (size_t)row * FDIM + col);
    float4 a = s[0], b = s[1];
    float n0 = fmaf(a.x, a.x, a.y * a.y);
    float n1 = fmaf(a.z, a.z, a.w * a.w);
    float n2 = fmaf(b.x, b.x, b.y * b.y);
    float n3 = fmaf(b.z, b.z, b.w * b.w);
    float ss = (n0 + n1) + (n2 + n3);
    ushort o[8];
    const float* f = &a.x;
#pragma unroll
    for (int k = 0; k < 4; ++k) {
        u32 u = __float_as_uint(f[k]);
        o[k] = (ushort)((u + 0x7fffu + ((u >> 16) & 1u)) >> 16);
    }
    const float* gg = &b.x;
#pragma unroll
    for (int k = 0; k < 4; ++k) {
        u32 u = __float_as_uint(gg[k]);
        o[4 + k] = (ushort)((u + 0x7fffu + ((u >> 16) & 1u)) >> 16);
    }
    dst[i] = *(uint4*)o;
    ss += __shfl_xor(ss, 16);
    ss += __shfl_xor(ss, 32);
    if (lane < 16) pn[w][r] = ss;
    __syncthreads();
    if (t < 32) {
        float v = (t < 16) ? (pn[0][t] + pn[1][t]) : (pn[2][t - 16] + pn[3][t - 16]);
        norms[blockIdx.x * 32 + t] = v;
    }
}

// ---- legacy scalar sample-hist kernels (fallback when ws is tight) ----
__global__ __launch_bounds__(256) void k_hist(const float* __restrict__ x, const float* __restrict__ X,
                                              const float* __restrict__ Xn, u32* __restrict__ hist,
                                              int N, int nsamp, int sj) {
    __shared__ unsigned char h8[NBUCKET * 256];
    int t = threadIdx.x;
    u32* h32 = (u32*)h8;
#pragma unroll
    for (int k = 0; k < 64; ++k) h32[k * 256 + t] = 0;
    __syncthreads();
    int q = blockIdx.x * 256 + t;
    float4 xv[16];
    float xn = load_query(x, q, xv);
    for (int j = 0; j < sj; ++j) {
        int s = blockIdx.y * sj + j;
        int p = s * 16;
        if (s < nsamp && p < N) {
            float dp = dot_row(xv, X + (size_t)p * FDIM);
            float d2 = fmaxf(xn + Xn[p] - 2.f * dp, 0.f);
            int b = min(NBUCKET - 1, (int)d2);
            int idx = b * 256 + t;
            unsigned char v = h8[idx];
            h8[idx] = (v == 255u) ? v : (unsigned char)(v + 1);
        }
    }
    __syncthreads();
#pragma unroll
    for (int w = 0; w < 128; ++w) {
        u32 v0 = h8[(2 * w) * 256 + t];
        u32 v1 = h8[(2 * w + 1) * 256 + t];
        if (v0 | v1) atomicAdd(&hist[(size_t)q * 128 + w], v0 | (v1 << 16));
    }
}

__global__ __launch_bounds__(256) void k_thresh(const u32* __restrict__ hist, float* __restrict__ Tq, int B) {
    int q = blockIdx.x * 256 + threadIdx.x;
    if (q >= B) return;
    const u32* h = hist + (size_t)q * 128;
    int cum = 0;
    float T = (float)NBUCKET;
    for (int w = 0; w < 128; ++w) {
        u32 v = h[w];
        cum += (int)(v & 0xffffu);
        if (cum >= KNN) { T = (float)(2 * w + 1); break; }
        cum += (int)(v >> 16);
        if (cum >= KNN) { T = (float)(2 * w + 2); break; }
    }
    Tq[q] = T + 2.0f;
}

// ---- K2 (MFMA sample pass): 1-wide d2a buckets (R13-proven; 0.5-wide saturates
// Gaussian d2 into bucket 255 -> thresh2 atomic hotspot, R14/R15 lesson).
// d2s TILED layout [tile][q][p_local]: each block writes one contiguous 16KB span.
__global__ __launch_bounds__(256, 3) void k_sample_d2(
        const uint4* __restrict__ xT, const uint4* __restrict__ XT,
        const float* __restrict__ qn, const float* __restrict__ Xn,
        unsigned char* __restrict__ d2s, int S) {
    int t = threadIdx.x;
    int w = t >> 6, lane = t & 63;
    int G = lane >> 4, r = lane & 15;
    int qg = blockIdx.x;
    int wq = qg * 128 + w * 32;
    int pb = blockIdx.y * 128;
    int Bq = gridDim.x * 128;   // total queries

    bf16x8 afr[2][2];
#pragma unroll
    for (int kk = 0; kk < 2; ++kk)
#pragma unroll
        for (int mi = 0; mi < 2; ++mi) {
            uint4 v = xT[(size_t)(((wq >> 4) + mi) * 2 + kk) * 64 + lane];
            afr[kk][mi] = *(bf16x8*)&v;
        }
    float qr[8];
#pragma unroll
    for (int e = 0; e < 8; ++e)
        qr[e] = qn[wq + (e >> 2) * 16 + G * 4 + (e & 3)];

    unsigned char* dtile = d2s + (size_t)blockIdx.y * Bq * 128;

#pragma unroll
    for (int half = 0; half < 2; ++half) {
        int nb = half * 4;
        bf16x8 bfr[4][2];
#pragma unroll
        for (int j = 0; j < 4; ++j) {
            int gp = (pb >> 4) + nb + j;
#pragma unroll
            for (int kk = 0; kk < 2; ++kk) {
                uint4 v = XT[(size_t)(gp * 2 + kk) * 64 + lane];
                bfr[j][kk] = *(bf16x8*)&v;
            }
        }
        float xnv[4];
#pragma unroll
        for (int j = 0; j < 4; ++j) xnv[j] = Xn[pb + (nb + j) * 16 + r];

        f32x4 acc[2][4];
#pragma unroll
        for (int mi = 0; mi < 2; ++mi)
#pragma unroll
            for (int j = 0; j < 4; ++j) acc[mi][j] = (f32x4){0.f, 0.f, 0.f, 0.f};
#pragma unroll
        for (int kk = 0; kk < 2; ++kk)
#pragma unroll
            for (int j = 0; j < 4; ++j) {
                acc[0][j] = __builtin_amdgcn_mfma_f32_16x16x32_bf16(afr[kk][0], bfr[j][kk], acc[0][j], 0, 0, 0);
                acc[1][j] = __builtin_amdgcn_mfma_f32_16x16x32_bf16(afr[kk][1], bfr[j][kk], acc[1][j], 0, 0, 0);
            }
#pragma unroll
        for (int j = 0; j < 4; ++j) {
            int pl = (nb + j) * 16 + r;   // p within tile, 0..127
            float xnp = xnv[j];
#pragma unroll
            for (int e = 0; e < 8; ++e) {
                float d2a = qr[e] + fmaf(-2.f, acc[e >> 2][j][e & 3], xnp);
                int b = (int)d2a;
                b = b < 0 ? 0 : (b > 255 ? 255 : b);
                int q = wq + (e >> 2) * 16 + G * 4 + (e & 3);
                dtile[(size_t)q * 128 + pl] = (unsigned char)b;
            }
        }
    }
}

// ---- K2b: per-query hist of 1-wide d2a buckets -> T = (b+1) + 2.
// Also zeroes ocnt[q] (replaces the ocnt memset; runs before the filter).
__global__ __launch_bounds__(256) void k_thresh2(const unsigned char* __restrict__ d2s,
                                                 float* __restrict__ Tq, u32* __restrict__ ocnt, int S) {
    __shared__ u32 h[4][NBUCKET];
    int t = threadIdx.x;
    int w = t >> 6;
    int q = blockIdx.x;
    int Bq = gridDim.x;
    if (t == 0) ocnt[q] = 0;
#pragma unroll
    for (int k = 0; k < 4; ++k) h[k][t] = 0;
    __syncthreads();
    const u32* base32 = (const u32*)d2s;
    int n32 = S >> 2;   // Stiles*32 u32 words per query
    for (int i = t; i < n32; i += 256) {
        int tile = i >> 5, c = i & 31;
        u32 v = base32[((size_t)tile * Bq + q) * 32 + c];
        u32* hw = h[w];
        atomicAdd(&hw[v & 255u], 1u);
        atomicAdd(&hw[(v >> 8) & 255u], 1u);
        atomicAdd(&hw[(v >> 16) & 255u], 1u);
        atomicAdd(&hw[v >> 24], 1u);
    }
    __syncthreads();
    u32 s = h[0][t] + h[1][t] + h[2][t] + h[3][t];
    h[0][t] = s;
    __syncthreads();
    if (t == 0) {
        int cum = 0;
        float T = 256.0f;
        for (int b = 0; b < NBUCKET; ++b) {
            cum += (int)h[0][b];
            if (cum >= KNN) { T = (float)(b + 1); break; }
        }
        Tq[q] = T + 2.0f;
    }
}

// ---- K3: MFMA filter, single 16KB LDS buffer, launch_bounds(256,4) (R13 config, best).
__global__ __launch_bounds__(256, 4) void k_mfma_filter(
        const uint4* __restrict__ xT, const uint4* __restrict__ XT,
        const float* __restrict__ qn, const float* __restrict__ Xn,
        const float* __restrict__ Tf,
        u32* __restrict__ cnt_seg, u32* __restrict__ list_seg,
        u32* __restrict__ ocnt, u32* __restrict__ olist,
        int N, int nStripsPad, int strip, int B) {
    __shared__ uint4 sbuf[1024];   // one 16 KB tile buffer
    __shared__ u32 ldsCnt[128];

    int t = threadIdx.x;
    int w = t >> 6, lane = t & 63;
    int G = lane >> 4, r = lane & 15;

    int bid = blockIdx.x;
    int qg = (bid >> 3) & 7;
    int sIdx = (bid & 7) | ((bid >> 6) << 3);
    int qbase = qg * 128;
    int wq = qbase + w * 32;

    if (t < 128) ldsCnt[t] = 0;

    bf16x8 afr[2][2];
#pragma unroll
    for (int kk = 0; kk < 2; ++kk)
#pragma unroll
        for (int mi = 0; mi < 2; ++mi) {
            uint4 v = xT[(size_t)(((wq >> 4) + mi) * 2 + kk) * 64 + lane];
            afr[kk][mi] = *(bf16x8*)&v;
        }
    float nT[8], qnr[8];
#pragma unroll
    for (int e = 0; e < 8; ++e) {
        int rl = wq + (e >> 2) * 16 + G * 4 + (e & 3);
        float qv = qn[rl];
        qnr[e] = qv;
        nT[e] = -0.5f * (Tf[rl] - qv);   // pass iff acc > nT[e]
    }

    // list in [q][s] layout: per-q contiguous row for k_final
    u32* segBase = list_seg + ((size_t)qbase * nStripsPad + (size_t)sIdx) * SEG;

    int pb0 = sIdx * strip * 128;
    int ntl = (pb0 < N) ? strip : 0;   // whole-strip padding blocks skip compute

    for (int s = 0; s < ntl; ++s) {
        int pb = pb0 + s * 128;
        // stage tile s (all waves cooperate; 16 KB contiguous)
        {
            const char* src = (const char*)XT + (size_t)(pb >> 4) * 2048 + w * 1024 + lane * 16;
            char* dst = (char*)&sbuf[0] + w * 1024;
            gload_lds16(src, dst);
            gload_lds16(src + 4096, dst + 4096);
            gload_lds16(src + 8192, dst + 8192);
            gload_lds16(src + 12288, dst + 12288);
        }
        __syncthreads();   // drains vmcnt -> staged data visible
        const uint4* cur = &sbuf[0];

#pragma unroll
        for (int half = 0; half < 2; ++half) {
            int nb = half * 4;
            bf16x8 bfr[4][2];
#pragma unroll
            for (int j = 0; j < 4; ++j) {
#pragma unroll
                for (int kk = 0; kk < 2; ++kk) {
                    uint4 v = cur[((nb + j) * 2 + kk) * 64 + lane];
                    bfr[j][kk] = *(bf16x8*)&v;
                }
            }
            float xnv[4], ai[4];
#pragma unroll
            for (int j = 0; j < 4; ++j) {
                xnv[j] = Xn[pb + (nb + j) * 16 + r];
                ai[j] = -0.5f * xnv[j];
            }

            f32x4 acc[2][4];
#pragma unroll
            for (int mi = 0; mi < 2; ++mi)
#pragma unroll
                for (int j = 0; j < 4; ++j) acc[mi][j] = (f32x4){ai[j], ai[j], ai[j], ai[j]};
#pragma unroll
            for (int kk = 0; kk < 2; ++kk)
#pragma unroll
                for (int j = 0; j < 4; ++j) {
                    acc[0][j] = __builtin_amdgcn_mfma_f32_16x16x32_bf16(afr[kk][0], bfr[j][kk], acc[0][j], 0, 0, 0);
                    acc[1][j] = __builtin_amdgcn_mfma_f32_16x16x32_bf16(afr[kk][1], bfr[j][kk], acc[1][j], 0, 0, 0);
                }
#pragma unroll
            for (int j = 0; j < 4; ++j) {
                int p = pb + (nb + j) * 16 + r;
                bool ce[8];
#pragma unroll
                for (int e = 0; e < 8; ++e)
                    ce[e] = acc[e >> 2][j][e & 3] > nT[e];
                if ((ce[0] | ce[1] | ce[2] | ce[3] | ce[4] | ce[5] | ce[6] | ce[7]) && p < N) {
#pragma unroll
                    for (int e = 0; e < 8; ++e) {
                        if (ce[e]) {
                            float d2a = fmaf(-2.f, acc[e >> 2][j][e & 3], qnr[e]);
                            d2a = d2a < 0.f ? 0.f : d2a;
                            u32 dq = (u32)(d2a * 32.f);
                            if (dq > 16383u) dq = 16383u;
                            u32 key = (dq << 18) | (u32)p;
                            int ql = w * 32 + (e >> 2) * 16 + G * 4 + (e & 3);
                            u32 slot = atomicAdd(&ldsCnt[ql], 1u);
                            if (slot < SEG) {
                                segBase[(size_t)ql * nStripsPad * SEG + slot] = key;
                            } else {
                                u32 gs = atomicAdd(&ocnt[qbase + ql], 1u);
                                if (gs < OCAP) olist[(size_t)(qbase + ql) * OCAP + gs] = key;
                            }
                        }
                    }
                }
            }
        }
        __syncthreads();   // all waves done with sbuf before next stage overwrites
    }

    if (ntl == 0) __syncthreads();   // uniform per block; aligns no-work blocks
    if (t < 128) cnt_seg[(size_t)sIdx * B + qbase + t] = min(ldsCnt[t], (u32)SEG);
}

// ---- K3 (scalar fallback, flat list + global atomics)
__global__ __launch_bounds__(256) void k_filter_scalar(const float* __restrict__ x, const float* __restrict__ X,
                                                       const float* __restrict__ Xn, const float* __restrict__ Tq,
                                                       u32* __restrict__ cnt, u32* __restrict__ list,
                                                       int N, int cap) {
    int t = threadIdx.x;
    int q = blockIdx.x * 256 + t;
    float4 xv[16];
    float xn = load_query(x, q, xv);
    float T = Tq[q];
    int base = blockIdx.y * 1024;
    int lim = min(1024, N - base);
    for (int j = 0; j < lim; ++j) {
        int p = base + j;
        float dp = dot_row(xv, X + (size_t)p * FDIM);
        float d2 = fmaxf(xn + Xn[p] - 2.f * dp, 0.f);
        if (d2 < T) {
            u32 slot = atomicAdd(&cnt[q], 1u);
            if (slot < (u32)cap) list[(size_t)q * cap + slot] = (u32)p;
        }
    }
}

// ---- K4: gather + band-select on approx d2 + pipelined exact rescore of the band only
//          + wave-0 butterfly top-32 + NN head
__global__ __launch_bounds__(256) void k_final(const float* __restrict__ x, const float* __restrict__ X,
                                               const float* __restrict__ y, const float* __restrict__ Xn,
                                               const float* __restrict__ Wg, const float* __restrict__ bg,
                                               const float* __restrict__ W1, const float* __restrict__ b1,
                                               const float* __restrict__ Wl, const float* __restrict__ bl,
                                               const u32* __restrict__ cnt_seg, const u32* __restrict__ list_seg,
                                               const u32* __restrict__ ocnt, const u32* __restrict__ olist,
                                               const u32* __restrict__ cnt_flat, const u32* __restrict__ list_flat,
                                               float* __restrict__ out, int nStripsPad, int cap_flat, int flat,
                                               int N, int B) {
    __shared__ u64 keys[MAXCAP];
    __shared__ u32 nsh;
    __shared__ u64 wk[4];
    __shared__ int wp[4];
    __shared__ u32 sel[KNN];
    __shared__ float gkc[KNN * 16];
    __shared__ float aggc[16];
    __shared__ float red[128];
    __shared__ u32 hist[2048];   // approx-d2 histogram; reused as band candidate list
    __shared__ u32 wtot[4];
    __shared__ u32 cutq_sh;
    __shared__ u32 nrs;

    int t = threadIdx.x;
    int w = t >> 6, lane = t & 63;
    int q = blockIdx.x;
    int m;

    if (flat) {
        m = (int)min(cnt_flat[q], (u32)cap_flat);
        const u32* lq = list_flat + (size_t)q * cap_flat;
        for (int i = t; i < m; i += 256) keys[i] = lq[i];
    } else {
        if (t == 0) nsh = 0;
        __syncthreads();
        for (int seg = t; seg < nStripsPad; seg += 256) {
            u32 c = cnt_seg[(size_t)seg * B + q];
            if (c) {
                u32 base = atomicAdd(&nsh, c);
                const u32* sp = list_seg + ((size_t)q * nStripsPad + seg) * SEG;
                for (u32 j = 0; j < c; ++j) {
                    u32 idx = base + j;
                    if (idx < MAXCAP) keys[idx] = sp[j];
                }
            }
        }
        __syncthreads();
        int m0 = (int)min(nsh, (u32)MAXCAP);
        int oc = (int)min(ocnt[q], (u32)OCAP);
        for (int i = t; i < oc; i += 256)
            if (m0 + i < MAXCAP) keys[m0 + i] = olist[(size_t)q * OCAP + i];
        m = min(m0 + oc, MAXCAP);
    }
    __syncthreads();

    // ---- Phase A: find approx 32nd-smallest d2 (quantized) and set the rescore cutoff.
    if (!flat) {
        for (int i = t; i < 2048; i += 256) hist[i] = 0;
        if (t == 0) cutq_sh = 0xFFFFFFFFu;
        __syncthreads();
        for (int i = t; i < m; i += 256) atomicAdd(&hist[((u32)keys[i]) >> 21], 1u);
        __syncthreads();
        u32 s = 0;
#pragma unroll
        for (int j = 0; j < 8; ++j) s += hist[t * 8 + j];
        u32 run = s;
#pragma unroll
        for (int off = 1; off < 64; off <<= 1) {
            u32 v = __shfl_up(run, off);
            if (lane >= off) run += v;
        }
        if (lane == 63) wtot[w] = run;
        __syncthreads();
        u32 wo = 0;
#pragma unroll
        for (int v = 0; v < 4; ++v) wo += (v < w) ? wtot[v] : 0u;
        u32 inc = wo + run;
        u32 exc = inc - s;
        if (exc < (u32)KNN && inc >= (u32)KNN) {
            u32 cum = exc;
#pragma unroll
            for (int j = 0; j < 8; ++j) {
                cum += hist[t * 8 + j];
                if (cum >= (u32)KNN) { cutq_sh = (u32)(((t * 8 + j + 1) << 3) + BANDQ); break; }
            }
        }
    }
    if (t == 0) nrs = 0;
    __syncthreads();
    u32 cutq = flat ? 0xFFFFFFFFu : cutq_sh;

    // ---- compact the band into cand[] (reuse hist storage)
    u32* cand = hist;
    for (int i = t; i < m; i += 256) {
        u32 k = (u32)keys[i];
        if ((k >> 18) <= cutq) cand[atomicAdd(&nrs, 1u)] = k & 0x3FFFFu;
    }
    __syncthreads();
    int mr = (int)min(nrs, (u32)MAXCAP);

    // ---- coalesced exact fp32 rescore of the band with 8-deep load pipeline.
    {
        int ch = lane & 15;
        int rsub = lane >> 4;  // 0..3
        float4 xq4 = ((const float4*)(x + (size_t)q * FDIM))[ch];
        float xs = fmaf(xq4.x, xq4.x, fmaf(xq4.y, xq4.y, fmaf(xq4.z, xq4.z, xq4.w * xq4.w)));
        xs += __shfl_xor(xs, 1);
        xs += __shfl_xor(xs, 2);
        xs += __shfl_xor(xs, 4);
        xs += __shfl_xor(xs, 8);
        float xn = xs;
        for (int base = w * 32; base < mr; base += 128) {
            int ri[8]; u32 pp[8]; bool val[8]; float4 vv[8];
#pragma unroll
            for (int u = 0; u < 8; ++u) {
                ri[u] = base + u * 4 + rsub;
                val[u] = ri[u] < mr;
                pp[u] = val[u] ? cand[ri[u]] : 0u;
            }
#pragma unroll
            for (int u = 0; u < 8; ++u)
                vv[u] = ((const float4*)(X + (size_t)pp[u] * FDIM))[ch];
#pragma unroll
            for (int u = 0; u < 8; ++u) {
                float part = fmaf(xq4.x, vv[u].x, fmaf(xq4.y, vv[u].y, fmaf(xq4.z, vv[u].z, xq4.w * vv[u].w)));
                part += __shfl_xor(part, 1);
                part += __shfl_xor(part, 2);
                part += __shfl_xor(part, 4);
                part += __shfl_xor(part, 8);
                if (val[u] && ch == 0) {
                    float d2 = fmaxf(xn + Xn[pp[u]] - 2.f * part, 0.f);
                    keys[ri[u]] = ((u64)__float_as_uint(d2) << 32) | pp[u];
                }
            }
        }
    }
    __syncthreads();

    if (mr <= 512) {
        if (w == 0) {
            u64 rk[8];
#pragma unroll
            for (int i = 0; i < 8; ++i) {
                int idx = lane + (i << 6);
                rk[i] = (idx < mr) ? keys[idx] : ~0ull;
            }
            for (int r = 0; r < KNN; ++r) {
                u64 bk = ~0ull;
                int bs = 0;
#pragma unroll
                for (int i = 0; i < 8; ++i)
                    if (rk[i] < bk) { bk = rk[i]; bs = i; }
                int bo = lane;
#pragma unroll
                for (int off = 1; off < 64; off <<= 1) {
                    u64 ok = __shfl_xor(bk, off);
                    int oo = __shfl_xor(bo, off);
                    if (ok < bk) { bk = ok; bo = oo; }
                }
                if (lane == bo) rk[bs] = ~0ull;
                if (lane == 0) sel[r] = (u32)bk;
            }
        }
        __syncthreads();
    } else {
        for (int r = 0; r < KNN; ++r) {
            u64 bk = ~0ull;
            int bp = -1;
            for (int i = t; i < mr; i += 256) {
                u64 k = keys[i];
                if (k < bk) { bk = k; bp = i; }
            }
#pragma unroll
            for (int off = 32; off > 0; off >>= 1) {
                u64 ok = __shfl_down(bk, off);
                int op = __shfl_down(bp, off);
                if (ok < bk) { bk = ok; bp = op; }
            }
            if (lane == 0) { wk[w] = bk; wp[w] = bp; }
            __syncthreads();
            if (t == 0) {
                u64 fb = wk[0];
                int fp = wp[0];
                for (int v = 1; v < 4; ++v)
                    if (wk[v] < fb) { fb = wk[v]; fp = wp[v]; }
                sel[r] = (u32)(fb & 0xffffffffu);
                if (fp >= 0) keys[fp] = ~0ull;
            }
            __syncthreads();
        }
    }

    int c = t & 15, kk = t >> 4;
#pragma unroll
    for (int rep = 0; rep < 2; ++rep) {
        int k = kk + 16 * rep;
        int nb = min((int)sel[k], N - 1);
        const float* Xr = X + (size_t)nb * FDIM;
        float acc = bg[c];
#pragma unroll
        for (int f = 0; f < FDIM; ++f) acc = fmaf(Xr[f], Wg[f * 16 + c], acc);
        acc = fmaf(y[nb], Wg[FDIM * 16 + c], acc);
        gkc[k * 16 + c] = tanhf(acc);
    }
    __syncthreads();
    if (t < 16) {
        float s = 0.f;
#pragma unroll
        for (int k = 0; k < KNN; ++k) s += gkc[k * 16 + t];
        aggc[t] = s;
    }
    __syncthreads();
    if (t < 128) {
        const float* xq = x + (size_t)q * FDIM;
        float acc = b1[t];
#pragma unroll
        for (int f = 0; f < FDIM; ++f) acc = fmaf(xq[f], W1[f * 128 + t], acc);
#pragma unroll
        for (int cc2 = 0; cc2 < 16; ++cc2) acc = fmaf(aggc[cc2], W1[(FDIM + cc2) * 128 + t], acc);
        red[t] = tanhf(acc) * Wl[t];
    }
    __syncthreads();
    for (int off = 64; off > 0; off >>= 1) {
        if (t < off) red[t] += red[t + off];
        __syncthreads();
    }
    if (t == 0) out[q] = 1.f / (1.f + expf(-(red[0] + bl[0])));
}

extern "C" void kernel_launch(void* const* d_in, const int* in_sizes, int n_in,
                              void* d_out, int out_size, void* d_ws, size_t ws_size,
                              hipStream_t stream) {
    const float* x  = (const float*)d_in[0];
    const float* X  = (const float*)d_in[1];
    const float* y  = (const float*)d_in[2];
    const float* Wg = (const float*)d_in[3];
    const float* bg = (const float*)d_in[4];
    const float* W1 = (const float*)d_in[5];
    const float* b1 = (const float*)d_in[6];
    const float* Wl = (const float*)d_in[7];
    const float* bl = (const float*)d_in[8];
    float* out = (float*)d_out;

    int B = in_sizes[0] / FDIM;  // 1024
    int N = in_sizes[1] / FDIM;  // 200000

    const int strip = 4;
    int nTiles = (N + 127) / 128;
    int nStrips = (nTiles + strip - 1) / strip;
    nStrips = (nStrips + 7) & ~7;
    int nStripsPad = nStrips;           // 392
    int Npad = nStrips * strip * 128;   // 200704

    char* w = (char*)d_ws;
    size_t off = 0;
    auto alloc = [&](size_t bytes) { void* p = w + off; off += (bytes + 255) & ~(size_t)255; return p; };
    float* Xn  = (float*)alloc((size_t)Npad * 4);
    float* qn  = (float*)alloc((size_t)B * 4);
    u32* hist  = (u32*)alloc((size_t)B * 512);
    float* Tq  = (float*)alloc((size_t)B * 4);
    u32* cnt   = (u32*)alloc((size_t)B * 4);

    size_t xTB = (size_t)B * 128;
    size_t XTB = (size_t)(Npad / 16) * 2048;
    size_t segCntB = (size_t)B * nStripsPad * 4;
    size_t segListB = (size_t)B * nStripsPad * SEG * 4;
    size_t ocntB = (size_t)B * 4;
    size_t olistB = (size_t)B * OCAP * 4;
    size_t rem = (ws_size > off) ? ws_size - off : 0;
    bool mfma_path = rem >= xTB + XTB + segCntB + segListB + ocntB + olistB + 4096;

    uint4* xT = nullptr; uint4* XT = nullptr;
    u32 *cnt_seg = nullptr, *list_seg = nullptr, *ocnt = nullptr, *olist = nullptr;
    u32* list_flat = nullptr; unsigned char* d2s = nullptr;
    int cap_flat = 64, Stiles = 0;
    if (mfma_path) {
        xT = (uint4*)alloc(xTB);
        XT = (uint4*)alloc(XTB);
        cnt_seg  = (u32*)alloc(segCntB);
        list_seg = (u32*)alloc(segListB);
        ocnt     = (u32*)alloc(ocntB);
        olist    = (u32*)alloc(olistB);
        rem = (ws_size > off) ? ws_size - off : 0;
        size_t st = rem / ((size_t)B * 128);
        Stiles = st > 100 ? 100 : (int)st;
        int maxFull = N / 128;
        if (Stiles > maxFull) Stiles = maxFull;
        if (Stiles >= 96) d2s = (unsigned char*)alloc((size_t)Stiles * 128 * B);
        else Stiles = 0;
    } else {
        size_t c = rem / ((size_t)B * 4);
        cap_flat = c > MAXCAP ? MAXCAP : (int)c;
        if (cap_flat < 64) cap_flat = 64;
        list_flat = (u32*)alloc((size_t)B * cap_flat * 4);
    }

    if (mfma_path) {
        hipMemsetAsync(Xn + N, 0, (size_t)(Npad - N) * 4, stream);
        size_t realXT = (size_t)(N / 16) * 2048;
        hipMemsetAsync((char*)XT + realXT, 0, XTB - realXT, stream);

        int nxu4 = B * 8, nXu4 = N * 8;
        if ((nxu4 & 255) == 0) {
            k_cvtT_norm<<<dim3(nxu4 / 256), 256, 0, stream>>>(x, xT, qn, nxu4);
        } else {
            k_xnorm<<<dim3((B + 255) / 256), 256, 0, stream>>>(x, qn, B);
            k_cvtT<<<dim3((nxu4 + 255) / 256), 256, 0, stream>>>(x, xT, nxu4);
        }
        if ((nXu4 & 255) == 0) {
            k_cvtT_norm<<<dim3(nXu4 / 256), 256, 0, stream>>>(X, XT, Xn, nXu4);
        } else {
            k_xnorm<<<dim3((N + 255) / 256), 256, 0, stream>>>(X, Xn, N);
            k_cvtT<<<dim3((nXu4 + 255) / 256), 256, 0, stream>>>(X, XT, nXu4);
        }

        if (Stiles > 0) {
            int S = Stiles * 128;
            k_sample_d2<<<dim3(8, Stiles), 256, 0, stream>>>(xT, XT, qn, Xn, d2s, S);
            k_thresh2<<<dim3(B), 256, 0, stream>>>(d2s, Tq, ocnt, S);
        } else {
            hipMemsetAsync(ocnt, 0, ocntB, stream);
            hipMemsetAsync(hist, 0, (size_t)B * 512, stream);
            int nsamp = (N + 15) / 16;
            int chunks = 128;
            int sj = (nsamp + chunks - 1) / chunks;
            k_hist<<<dim3(B / 256, chunks), 256, 0, stream>>>(x, X, Xn, hist, N, nsamp, sj);
            k_thresh<<<dim3((B + 255) / 256), 256, 0, stream>>>(hist, Tq, B);
        }

        k_mfma_filter<<<dim3(8 * nStrips), 256, 0, stream>>>(
            xT, XT, qn, Xn, Tq, cnt_seg, list_seg, ocnt, olist, N, nStripsPad, strip, B);

        k_final<<<dim3(B), 256, 0, stream>>>(x, X, y, Xn, Wg, bg, W1, b1, Wl, bl,
                                             cnt_seg, list_seg, ocnt, olist,
                                             nullptr, nullptr, out, nStripsPad, 0, 0, N, B);
    } else {
        k_xnorm<<<dim3((N + 255) / 256), 256, 0, stream>>>(X, Xn, N);
        k_xnorm<<<dim3((B + 255) / 256), 256, 0, stream>>>(x, qn, B);
        hipMemsetAsync(cnt, 0, (size_t)B * 4, stream);
        hipMemsetAsync(hist, 0, (size_t)B * 512, stream);
        int nsamp = (N + 15) / 16;
        int chunks = 128;
        int sj = (nsamp + chunks - 1) / chunks;
        k_hist<<<dim3(B / 256, chunks), 256, 0, stream>>>(x, X, Xn, hist, N, nsamp, sj);
        k_thresh<<<dim3((B + 255) / 256), 256, 0, stream>>>(hist, Tq, B);
        k_filter_scalar<<<dim3(B / 256, (N + 1023) / 1024), 256, 0, stream>>>(
            x, X, Xn, Tq, cnt, list_flat, N, cap_flat);
        k_final<<<dim3(B), 256, 0, stream>>>(x, X, y, Xn, Wg, bg, W1, b1, Wl, bl,
                                             nullptr, nullptr, nullptr, nullptr,
                                             cnt, list_flat, out, nStripsPad, cap_flat, 1, N, B);
    }
}

// Round 17
// 238.198 us; speedup vs baseline: 1.1508x; 1.0279x over previous
//
#include <hip/hip_runtime.h>
#include <cstdint>

#define FDIM 64
#define KNN 32
#define NBUCKET 256
#define MAXCAP 2048
#define SEG 8
#define OCAP 512
// band selection: keys from the MFMA filter are (d2_quant<<18)|p with d2_quant = floor(32*d2a),
// p < 2^18 (N=200000 < 262144). BANDQ = 96 -> 3.0 in d2 units; covers 2*eps for bf16 dot
// error eps up to ~1.45 (measured/typical eps ~0.1-0.3, 4-sigma bound ~0.6).
// R7: m ~= N*P(d2 < sample_q(32/S)+margin); S=12800 safe under MAXCAP.
// R8: filter time scales with m via the hit path.  R9: per-e __any branches regress.
// R10: hybrid seg layout (cnt[s][q], list[q][s]).  R11: d2s tiling neutral.
// R12: launch_bounds(256,8) caps unified VGPR+AGPR -> spill catastrophe.
// R13: single 16KB buffer + (256,4): best total (244.2us).
// R14/R15: 0.5-wide buckets saturate Gaussian d2 -> thresh2 atomic hotspot (~25us);
//   reverted. R14-vs-R15 controlled A/B: cvt mega-kernel fusion itself = -4.6us.
// R17: R16 config (1-wide buckets, ocnt-in-thresh2) + cvt fusion re-added.
#define BANDQ 96

typedef unsigned int u32;
typedef unsigned long long u64;
typedef __attribute__((ext_vector_type(8))) short bf16x8;
typedef __attribute__((ext_vector_type(4))) float f32x4;

// async global->LDS, 16B per lane. LDS dest is wave-uniform base + lane*16 (HW rule).
__device__ __forceinline__ void gload_lds16(const void* g, void* l) {
    __builtin_amdgcn_global_load_lds(
        (const __attribute__((address_space(1))) unsigned int*)g,
        (__attribute__((address_space(3))) unsigned int*)l,
        16, 0, 0);
}

// ---- shared fp32 helpers
__device__ __forceinline__ float load_query(const float* __restrict__ x, int q, float4* xv) {
    const float4* xp = (const float4*)(x + (size_t)q * FDIM);
    float n0 = 0.f, n1 = 0.f, n2 = 0.f, n3 = 0.f;
#pragma unroll
    for (int k = 0; k < 16; ++k) {
        float4 v = xp[k];
        xv[k] = v;
        n0 = fmaf(v.x, v.x, n0); n1 = fmaf(v.y, v.y, n1);
        n2 = fmaf(v.z, v.z, n2); n3 = fmaf(v.w, v.w, n3);
    }
    return (n0 + n1) + (n2 + n3);
}

__device__ __forceinline__ float dot_row(const float4* __restrict__ xv, const float* __restrict__ row) {
    const float4* rv = (const float4*)row;
    float d0 = 0.f, d1 = 0.f, d2 = 0.f, d3 = 0.f;
#pragma unroll
    for (int k = 0; k < 16; ++k) {
        float4 r = rv[k];
        float4 a = xv[k];
        d0 = fmaf(a.x, r.x, d0); d1 = fmaf(a.y, r.y, d1);
        d2 = fmaf(a.z, r.z, d2); d3 = fmaf(a.w, r.w, d3);
    }
    return (d0 + d1) + (d2 + d3);
}

// ---- K1: row norms (fallback path)
__global__ __launch_bounds__(256) void k_xnorm(const float* __restrict__ X, float* __restrict__ Xn, int N) {
    int i = blockIdx.x * 256 + threadIdx.x;
    if (i >= N) return;
    const float4* r = (const float4*)(X + (size_t)i * FDIM);
    float d0 = 0.f, d1 = 0.f, d2 = 0.f, d3 = 0.f;
#pragma unroll
    for (int k = 0; k < 16; ++k) {
        float4 v = r[k];
        d0 = fmaf(v.x, v.x, d0); d1 = fmaf(v.y, v.y, d1);
        d2 = fmaf(v.z, v.z, d2); d3 = fmaf(v.w, v.w, d3);
    }
    Xn[i] = (d0 + d1) + (d2 + d3);
}

// ---- K1b: fused fp32->bf16 (RNE) + transpose (no norm; fallback).
__global__ __launch_bounds__(256) void k_cvtT(const float* __restrict__ src, uint4* __restrict__ dst, int n_u4) {
    int i = blockIdx.x * 256 + threadIdx.x;
    if (i >= n_u4) return;
    int lane = i & 63;
    int kk = (i >> 6) & 1;
    int g = i >> 7;
    int row = g * 16 + (lane & 15);
    int col = kk * 32 + (lane >> 4) * 8;
    const float4* s = (const float4*)(src + (size_t)row * FDIM + col);
    float4 a = s[0], b = s[1];
    ushort o[8];
    const float* f = &a.x;
#pragma unroll
    for (int k = 0; k < 4; ++k) {
        u32 u = __float_as_uint(f[k]);
        o[k] = (ushort)((u + 0x7fffu + ((u >> 16) & 1u)) >> 16);
    }
    const float* gg = &b.x;
#pragma unroll
    for (int k = 0; k < 4; ++k) {
        u32 u = __float_as_uint(gg[k]);
        o[4 + k] = (ushort)((u + 0x7fffu + ((u >> 16) & 1u)) >> 16);
    }
    dst[i] = *(uint4*)o;
}

// ---- K1c: fused cvtT + row norms (single-source; fallback).
__global__ __launch_bounds__(256) void k_cvtT_norm(const float* __restrict__ src, uint4* __restrict__ dst,
                                                   float* __restrict__ norms, int n_u4) {
    __shared__ float pn[4][16];
    int t = threadIdx.x;
    int i = blockIdx.x * 256 + t;
    int lane = t & 63;
    int w = t >> 6;
    int kk = (i >> 6) & 1;
    int g = i >> 7;
    int r = lane & 15;
    int row = g * 16 + r;
    int col = kk * 32 + (lane >> 4) * 8;
    const float4* s = (const float4*)(src + (size_t)row * FDIM + col);
    float4 a = s[0], b = s[1];
    float n0 = fmaf(a.x, a.x, a.y * a.y);
    float n1 = fmaf(a.z, a.z, a.w * a.w);
    float n2 = fmaf(b.x, b.x, b.y * b.y);
    float n3 = fmaf(b.z, b.z, b.w * b.w);
    float ss = (n0 + n1) + (n2 + n3);
    ushort o[8];
    const float* f = &a.x;
#pragma unroll
    for (int k = 0; k < 4; ++k) {
        u32 u = __float_as_uint(f[k]);
        o[k] = (ushort)((u + 0x7fffu + ((u >> 16) & 1u)) >> 16);
    }
    const float* gg = &b.x;
#pragma unroll
    for (int k = 0; k < 4; ++k) {
        u32 u = __float_as_uint(gg[k]);
        o[4 + k] = (ushort)((u + 0x7fffu + ((u >> 16) & 1u)) >> 16);
    }
    dst[i] = *(uint4*)o;
    ss += __shfl_xor(ss, 16);
    ss += __shfl_xor(ss, 32);
    if (lane < 16) pn[w][r] = ss;
    __syncthreads();
    if (t < 32) {
        float v = (t < 16) ? (pn[0][t] + pn[1][t]) : (pn[2][t - 16] + pn[3][t - 16]);
        norms[blockIdx.x * 32 + t] = v;
    }
}

// ---- K1d: ONE launch covering x (xBlocks) then X (padded to Npad rows).
// Rows >= realRows write zero fragments + zero norms (replaces the two padding memsets).
// Requires rows%32==0 per source (B=1024, N=200000, Npad all multiples of 32).
// R14-vs-R15 A/B: this fusion = -4.6us (fewer dispatches + no memset drain gaps).
__global__ __launch_bounds__(256) void k_cvtT_norm2(
        const float* __restrict__ xsrc, const float* __restrict__ Xsrc,
        uint4* __restrict__ xdst, uint4* __restrict__ Xdst,
        float* __restrict__ qn, float* __restrict__ Xn,
        int xBlocks, int xRows, int XRowsReal) {
    __shared__ float pn[4][16];
    int t = threadIdx.x;
    int lane = t & 63;
    int w = t >> 6;
    int r = lane & 15;
    const float* src; uint4* dst; float* norms; int realRows; int lb;
    if ((int)blockIdx.x < xBlocks) {
        lb = blockIdx.x; src = xsrc; dst = xdst; norms = qn; realRows = xRows;
    } else {
        lb = blockIdx.x - xBlocks; src = Xsrc; dst = Xdst; norms = Xn; realRows = XRowsReal;
    }
    int i = lb * 256 + t;
    int kk = (i >> 6) & 1;
    int g = i >> 7;
    int row = g * 16 + r;
    int col = kk * 32 + (lane >> 4) * 8;
    float4 a = {0.f, 0.f, 0.f, 0.f}, b = {0.f, 0.f, 0.f, 0.f};
    if (row < realRows) {
        const float4* s = (const float4*)(src + (size_t)row * FDIM + col);
        a = s[0]; b = s[1];
    }
    float n0 = fmaf(a.x, a.x, a.y * a.y);
    float n1 = fmaf(a.z, a.z, a.w * a.w);
    float n2 = fmaf(b.x, b.x, b.y * b.y);
    float n3 = fmaf(b.z, b.z, b.w * b.w);
    float ss = (n0 + n1) + (n2 + n3);
    ushort o[8];
    const float* f = &a.x;
#pragma unroll
    for (int k = 0; k < 4; ++k) {
        u32 u = __float_as_uint(f[k]);
        o[k] = (ushort)((u + 0x7fffu + ((u >> 16) & 1u)) >> 16);
    }
    const float* gg = &b.x;
#pragma unroll
    for (int k = 0; k < 4; ++k) {
        u32 u = __float_as_uint(gg[k]);
        o[4 + k] = (ushort)((u + 0x7fffu + ((u >> 16) & 1u)) >> 16);
    }
    dst[i] = *(uint4*)o;
    ss += __shfl_xor(ss, 16);
    ss += __shfl_xor(ss, 32);
    if (lane < 16) pn[w][r] = ss;
    __syncthreads();
    if (t < 32) {
        float v = (t < 16) ? (pn[0][t] + pn[1][t]) : (pn[2][t - 16] + pn[3][t - 16]);
        norms[lb * 32 + t] = v;
    }
}

// ---- legacy scalar sample-hist kernels (fallback when ws is tight) ----
__global__ __launch_bounds__(256) void k_hist(const float* __restrict__ x, const float* __restrict__ X,
                                              const float* __restrict__ Xn, u32* __restrict__ hist,
                                              int N, int nsamp, int sj) {
    __shared__ unsigned char h8[NBUCKET * 256];
    int t = threadIdx.x;
    u32* h32 = (u32*)h8;
#pragma unroll
    for (int k = 0; k < 64; ++k) h32[k * 256 + t] = 0;
    __syncthreads();
    int q = blockIdx.x * 256 + t;
    float4 xv[16];
    float xn = load_query(x, q, xv);
    for (int j = 0; j < sj; ++j) {
        int s = blockIdx.y * sj + j;
        int p = s * 16;
        if (s < nsamp && p < N) {
            float dp = dot_row(xv, X + (size_t)p * FDIM);
            float d2 = fmaxf(xn + Xn[p] - 2.f * dp, 0.f);
            int b = min(NBUCKET - 1, (int)d2);
            int idx = b * 256 + t;
            unsigned char v = h8[idx];
            h8[idx] = (v == 255u) ? v : (unsigned char)(v + 1);
        }
    }
    __syncthreads();
#pragma unroll
    for (int w = 0; w < 128; ++w) {
        u32 v0 = h8[(2 * w) * 256 + t];
        u32 v1 = h8[(2 * w + 1) * 256 + t];
        if (v0 | v1) atomicAdd(&hist[(size_t)q * 128 + w], v0 | (v1 << 16));
    }
}

__global__ __launch_bounds__(256) void k_thresh(const u32* __restrict__ hist, float* __restrict__ Tq, int B) {
    int q = blockIdx.x * 256 + threadIdx.x;
    if (q >= B) return;
    const u32* h = hist + (size_t)q * 128;
    int cum = 0;
    float T = (float)NBUCKET;
    for (int w = 0; w < 128; ++w) {
        u32 v = h[w];
        cum += (int)(v & 0xffffu);
        if (cum >= KNN) { T = (float)(2 * w + 1); break; }
        cum += (int)(v >> 16);
        if (cum >= KNN) { T = (float)(2 * w + 2); break; }
    }
    Tq[q] = T + 2.0f;
}

// ---- K2 (MFMA sample pass): 1-wide d2a buckets (R13-proven).
// d2s TILED layout [tile][q][p_local]: each block writes one contiguous 16KB span.
__global__ __launch_bounds__(256, 3) void k_sample_d2(
        const uint4* __restrict__ xT, const uint4* __restrict__ XT,
        const float* __restrict__ qn, const float* __restrict__ Xn,
        unsigned char* __restrict__ d2s, int S) {
    int t = threadIdx.x;
    int w = t >> 6, lane = t & 63;
    int G = lane >> 4, r = lane & 15;
    int qg = blockIdx.x;
    int wq = qg * 128 + w * 32;
    int pb = blockIdx.y * 128;
    int Bq = gridDim.x * 128;   // total queries

    bf16x8 afr[2][2];
#pragma unroll
    for (int kk = 0; kk < 2; ++kk)
#pragma unroll
        for (int mi = 0; mi < 2; ++mi) {
            uint4 v = xT[(size_t)(((wq >> 4) + mi) * 2 + kk) * 64 + lane];
            afr[kk][mi] = *(bf16x8*)&v;
        }
    float qr[8];
#pragma unroll
    for (int e = 0; e < 8; ++e)
        qr[e] = qn[wq + (e >> 2) * 16 + G * 4 + (e & 3)];

    unsigned char* dtile = d2s + (size_t)blockIdx.y * Bq * 128;

#pragma unroll
    for (int half = 0; half < 2; ++half) {
        int nb = half * 4;
        bf16x8 bfr[4][2];
#pragma unroll
        for (int j = 0; j < 4; ++j) {
            int gp = (pb >> 4) + nb + j;
#pragma unroll
            for (int kk = 0; kk < 2; ++kk) {
                uint4 v = XT[(size_t)(gp * 2 + kk) * 64 + lane];
                bfr[j][kk] = *(bf16x8*)&v;
            }
        }
        float xnv[4];
#pragma unroll
        for (int j = 0; j < 4; ++j) xnv[j] = Xn[pb + (nb + j) * 16 + r];

        f32x4 acc[2][4];
#pragma unroll
        for (int mi = 0; mi < 2; ++mi)
#pragma unroll
            for (int j = 0; j < 4; ++j) acc[mi][j] = (f32x4){0.f, 0.f, 0.f, 0.f};
#pragma unroll
        for (int kk = 0; kk < 2; ++kk)
#pragma unroll
            for (int j = 0; j < 4; ++j) {
                acc[0][j] = __builtin_amdgcn_mfma_f32_16x16x32_bf16(afr[kk][0], bfr[j][kk], acc[0][j], 0, 0, 0);
                acc[1][j] = __builtin_amdgcn_mfma_f32_16x16x32_bf16(afr[kk][1], bfr[j][kk], acc[1][j], 0, 0, 0);
            }
#pragma unroll
        for (int j = 0; j < 4; ++j) {
            int pl = (nb + j) * 16 + r;   // p within tile, 0..127
            float xnp = xnv[j];
#pragma unroll
            for (int e = 0; e < 8; ++e) {
                float d2a = qr[e] + fmaf(-2.f, acc[e >> 2][j][e & 3], xnp);
                int b = (int)d2a;
                b = b < 0 ? 0 : (b > 255 ? 255 : b);
                int q = wq + (e >> 2) * 16 + G * 4 + (e & 3);
                dtile[(size_t)q * 128 + pl] = (unsigned char)b;
            }
        }
    }
}

// ---- K2b: per-query hist of 1-wide d2a buckets -> T = (b+1) + 2.
// Also zeroes ocnt[q] (replaces the ocnt memset; runs before the filter).
__global__ __launch_bounds__(256) void k_thresh2(const unsigned char* __restrict__ d2s,
                                                 float* __restrict__ Tq, u32* __restrict__ ocnt, int S) {
    __shared__ u32 h[4][NBUCKET];
    int t = threadIdx.x;
    int w = t >> 6;
    int q = blockIdx.x;
    int Bq = gridDim.x;
    if (t == 0) ocnt[q] = 0;
#pragma unroll
    for (int k = 0; k < 4; ++k) h[k][t] = 0;
    __syncthreads();
    const u32* base32 = (const u32*)d2s;
    int n32 = S >> 2;   // Stiles*32 u32 words per query
    for (int i = t; i < n32; i += 256) {
        int tile = i >> 5, c = i & 31;
        u32 v = base32[((size_t)tile * Bq + q) * 32 + c];
        u32* hw = h[w];
        atomicAdd(&hw[v & 255u], 1u);
        atomicAdd(&hw[(v >> 8) & 255u], 1u);
        atomicAdd(&hw[(v >> 16) & 255u], 1u);
        atomicAdd(&hw[v >> 24], 1u);
    }
    __syncthreads();
    u32 s = h[0][t] + h[1][t] + h[2][t] + h[3][t];
    h[0][t] = s;
    __syncthreads();
    if (t == 0) {
        int cum = 0;
        float T = 256.0f;
        for (int b = 0; b < NBUCKET; ++b) {
            cum += (int)h[0][b];
            if (cum >= KNN) { T = (float)(b + 1); break; }
        }
        Tq[q] = T + 2.0f;
    }
}

// ---- K3: MFMA filter, single 16KB LDS buffer, launch_bounds(256,4) (R13 config, best).
__global__ __launch_bounds__(256, 4) void k_mfma_filter(
        const uint4* __restrict__ xT, const uint4* __restrict__ XT,
        const float* __restrict__ qn, const float* __restrict__ Xn,
        const float* __restrict__ Tf,
        u32* __restrict__ cnt_seg, u32* __restrict__ list_seg,
        u32* __restrict__ ocnt, u32* __restrict__ olist,
        int N, int nStripsPad, int strip, int B) {
    __shared__ uint4 sbuf[1024];   // one 16 KB tile buffer
    __shared__ u32 ldsCnt[128];

    int t = threadIdx.x;
    int w = t >> 6, lane = t & 63;
    int G = lane >> 4, r = lane & 15;

    int bid = blockIdx.x;
    int qg = (bid >> 3) & 7;
    int sIdx = (bid & 7) | ((bid >> 6) << 3);
    int qbase = qg * 128;
    int wq = qbase + w * 32;

    if (t < 128) ldsCnt[t] = 0;

    bf16x8 afr[2][2];
#pragma unroll
    for (int kk = 0; kk < 2; ++kk)
#pragma unroll
        for (int mi = 0; mi < 2; ++mi) {
            uint4 v = xT[(size_t)(((wq >> 4) + mi) * 2 + kk) * 64 + lane];
            afr[kk][mi] = *(bf16x8*)&v;
        }
    float nT[8], qnr[8];
#pragma unroll
    for (int e = 0; e < 8; ++e) {
        int rl = wq + (e >> 2) * 16 + G * 4 + (e & 3);
        float qv = qn[rl];
        qnr[e] = qv;
        nT[e] = -0.5f * (Tf[rl] - qv);   // pass iff acc > nT[e]
    }

    // list in [q][s] layout: per-q contiguous row for k_final
    u32* segBase = list_seg + ((size_t)qbase * nStripsPad + (size_t)sIdx) * SEG;

    int pb0 = sIdx * strip * 128;
    int ntl = (pb0 < N) ? strip : 0;   // whole-strip padding blocks skip compute

    for (int s = 0; s < ntl; ++s) {
        int pb = pb0 + s * 128;
        // stage tile s (all waves cooperate; 16 KB contiguous)
        {
            const char* src = (const char*)XT + (size_t)(pb >> 4) * 2048 + w * 1024 + lane * 16;
            char* dst = (char*)&sbuf[0] + w * 1024;
            gload_lds16(src, dst);
            gload_lds16(src + 4096, dst + 4096);
            gload_lds16(src + 8192, dst + 8192);
            gload_lds16(src + 12288, dst + 12288);
        }
        __syncthreads();   // drains vmcnt -> staged data visible
        const uint4* cur = &sbuf[0];

#pragma unroll
        for (int half = 0; half < 2; ++half) {
            int nb = half * 4;
            bf16x8 bfr[4][2];
#pragma unroll
            for (int j = 0; j < 4; ++j) {
#pragma unroll
                for (int kk = 0; kk < 2; ++kk) {
                    uint4 v = cur[((nb + j) * 2 + kk) * 64 + lane];
                    bfr[j][kk] = *(bf16x8*)&v;
                }
            }
            float xnv[4], ai[4];
#pragma unroll
            for (int j = 0; j < 4; ++j) {
                xnv[j] = Xn[pb + (nb + j) * 16 + r];
                ai[j] = -0.5f * xnv[j];
            }

            f32x4 acc[2][4];
#pragma unroll
            for (int mi = 0; mi < 2; ++mi)
#pragma unroll
                for (int j = 0; j < 4; ++j) acc[mi][j] = (f32x4){ai[j], ai[j], ai[j], ai[j]};
#pragma unroll
            for (int kk = 0; kk < 2; ++kk)
#pragma unroll
                for (int j = 0; j < 4; ++j) {
                    acc[0][j] = __builtin_amdgcn_mfma_f32_16x16x32_bf16(afr[kk][0], bfr[j][kk], acc[0][j], 0, 0, 0);
                    acc[1][j] = __builtin_amdgcn_mfma_f32_16x16x32_bf16(afr[kk][1], bfr[j][kk], acc[1][j], 0, 0, 0);
                }
#pragma unroll
            for (int j = 0; j < 4; ++j) {
                int p = pb + (nb + j) * 16 + r;
                bool ce[8];
#pragma unroll
                for (int e = 0; e < 8; ++e)
                    ce[e] = acc[e >> 2][j][e & 3] > nT[e];
                if ((ce[0] | ce[1] | ce[2] | ce[3] | ce[4] | ce[5] | ce[6] | ce[7]) && p < N) {
#pragma unroll
                    for (int e = 0; e < 8; ++e) {
                        if (ce[e]) {
                            float d2a = fmaf(-2.f, acc[e >> 2][j][e & 3], qnr[e]);
                            d2a = d2a < 0.f ? 0.f : d2a;
                            u32 dq = (u32)(d2a * 32.f);
                            if (dq > 16383u) dq = 16383u;
                            u32 key = (dq << 18) | (u32)p;
                            int ql = w * 32 + (e >> 2) * 16 + G * 4 + (e & 3);
                            u32 slot = atomicAdd(&ldsCnt[ql], 1u);
                            if (slot < SEG) {
                                segBase[(size_t)ql * nStripsPad * SEG + slot] = key;
                            } else {
                                u32 gs = atomicAdd(&ocnt[qbase + ql], 1u);
                                if (gs < OCAP) olist[(size_t)(qbase + ql) * OCAP + gs] = key;
                            }
                        }
                    }
                }
            }
        }
        __syncthreads();   // all waves done with sbuf before next stage overwrites
    }

    if (ntl == 0) __syncthreads();   // uniform per block; aligns no-work blocks
    if (t < 128) cnt_seg[(size_t)sIdx * B + qbase + t] = min(ldsCnt[t], (u32)SEG);
}

// ---- K3 (scalar fallback, flat list + global atomics)
__global__ __launch_bounds__(256) void k_filter_scalar(const float* __restrict__ x, const float* __restrict__ X,
                                                       const float* __restrict__ Xn, const float* __restrict__ Tq,
                                                       u32* __restrict__ cnt, u32* __restrict__ list,
                                                       int N, int cap) {
    int t = threadIdx.x;
    int q = blockIdx.x * 256 + t;
    float4 xv[16];
    float xn = load_query(x, q, xv);
    float T = Tq[q];
    int base = blockIdx.y * 1024;
    int lim = min(1024, N - base);
    for (int j = 0; j < lim; ++j) {
        int p = base + j;
        float dp = dot_row(xv, X + (size_t)p * FDIM);
        float d2 = fmaxf(xn + Xn[p] - 2.f * dp, 0.f);
        if (d2 < T) {
            u32 slot = atomicAdd(&cnt[q], 1u);
            if (slot < (u32)cap) list[(size_t)q * cap + slot] = (u32)p;
        }
    }
}

// ---- K4: gather + band-select on approx d2 + pipelined exact rescore of the band only
//          + wave-0 butterfly top-32 + NN head
__global__ __launch_bounds__(256) void k_final(const float* __restrict__ x, const float* __restrict__ X,
                                               const float* __restrict__ y, const float* __restrict__ Xn,
                                               const float* __restrict__ Wg, const float* __restrict__ bg,
                                               const float* __restrict__ W1, const float* __restrict__ b1,
                                               const float* __restrict__ Wl, const float* __restrict__ bl,
                                               const u32* __restrict__ cnt_seg, const u32* __restrict__ list_seg,
                                               const u32* __restrict__ ocnt, const u32* __restrict__ olist,
                                               const u32* __restrict__ cnt_flat, const u32* __restrict__ list_flat,
                                               float* __restrict__ out, int nStripsPad, int cap_flat, int flat,
                                               int N, int B) {
    __shared__ u64 keys[MAXCAP];
    __shared__ u32 nsh;
    __shared__ u64 wk[4];
    __shared__ int wp[4];
    __shared__ u32 sel[KNN];
    __shared__ float gkc[KNN * 16];
    __shared__ float aggc[16];
    __shared__ float red[128];
    __shared__ u32 hist[2048];   // approx-d2 histogram; reused as band candidate list
    __shared__ u32 wtot[4];
    __shared__ u32 cutq_sh;
    __shared__ u32 nrs;

    int t = threadIdx.x;
    int w = t >> 6, lane = t & 63;
    int q = blockIdx.x;
    int m;

    if (flat) {
        m = (int)min(cnt_flat[q], (u32)cap_flat);
        const u32* lq = list_flat + (size_t)q * cap_flat;
        for (int i = t; i < m; i += 256) keys[i] = lq[i];
    } else {
        if (t == 0) nsh = 0;
        __syncthreads();
        for (int seg = t; seg < nStripsPad; seg += 256) {
            u32 c = cnt_seg[(size_t)seg * B + q];
            if (c) {
                u32 base = atomicAdd(&nsh, c);
                const u32* sp = list_seg + ((size_t)q * nStripsPad + seg) * SEG;
                for (u32 j = 0; j < c; ++j) {
                    u32 idx = base + j;
                    if (idx < MAXCAP) keys[idx] = sp[j];
                }
            }
        }
        __syncthreads();
        int m0 = (int)min(nsh, (u32)MAXCAP);
        int oc = (int)min(ocnt[q], (u32)OCAP);
        for (int i = t; i < oc; i += 256)
            if (m0 + i < MAXCAP) keys[m0 + i] = olist[(size_t)q * OCAP + i];
        m = min(m0 + oc, MAXCAP);
    }
    __syncthreads();

    // ---- Phase A: find approx 32nd-smallest d2 (quantized) and set the rescore cutoff.
    if (!flat) {
        for (int i = t; i < 2048; i += 256) hist[i] = 0;
        if (t == 0) cutq_sh = 0xFFFFFFFFu;
        __syncthreads();
        for (int i = t; i < m; i += 256) atomicAdd(&hist[((u32)keys[i]) >> 21], 1u);
        __syncthreads();
        u32 s = 0;
#pragma unroll
        for (int j = 0; j < 8; ++j) s += hist[t * 8 + j];
        u32 run = s;
#pragma unroll
        for (int off = 1; off < 64; off <<= 1) {
            u32 v = __shfl_up(run, off);
            if (lane >= off) run += v;
        }
        if (lane == 63) wtot[w] = run;
        __syncthreads();
        u32 wo = 0;
#pragma unroll
        for (int v = 0; v < 4; ++v) wo += (v < w) ? wtot[v] : 0u;
        u32 inc = wo + run;
        u32 exc = inc - s;
        if (exc < (u32)KNN && inc >= (u32)KNN) {
            u32 cum = exc;
#pragma unroll
            for (int j = 0; j < 8; ++j) {
                cum += hist[t * 8 + j];
                if (cum >= (u32)KNN) { cutq_sh = (u32)(((t * 8 + j + 1) << 3) + BANDQ); break; }
            }
        }
    }
    if (t == 0) nrs = 0;
    __syncthreads();
    u32 cutq = flat ? 0xFFFFFFFFu : cutq_sh;

    // ---- compact the band into cand[] (reuse hist storage)
    u32* cand = hist;
    for (int i = t; i < m; i += 256) {
        u32 k = (u32)keys[i];
        if ((k >> 18) <= cutq) cand[atomicAdd(&nrs, 1u)] = k & 0x3FFFFu;
    }
    __syncthreads();
    int mr = (int)min(nrs, (u32)MAXCAP);

    // ---- coalesced exact fp32 rescore of the band with 8-deep load pipeline.
    {
        int ch = lane & 15;
        int rsub = lane >> 4;  // 0..3
        float4 xq4 = ((const float4*)(x + (size_t)q * FDIM))[ch];
        float xs = fmaf(xq4.x, xq4.x, fmaf(xq4.y, xq4.y, fmaf(xq4.z, xq4.z, xq4.w * xq4.w)));
        xs += __shfl_xor(xs, 1);
        xs += __shfl_xor(xs, 2);
        xs += __shfl_xor(xs, 4);
        xs += __shfl_xor(xs, 8);
        float xn = xs;
        for (int base = w * 32; base < mr; base += 128) {
            int ri[8]; u32 pp[8]; bool val[8]; float4 vv[8];
#pragma unroll
            for (int u = 0; u < 8; ++u) {
                ri[u] = base + u * 4 + rsub;
                val[u] = ri[u] < mr;
                pp[u] = val[u] ? cand[ri[u]] : 0u;
            }
#pragma unroll
            for (int u = 0; u < 8; ++u)
                vv[u] = ((const float4*)(X + (size_t)pp[u] * FDIM))[ch];
#pragma unroll
            for (int u = 0; u < 8; ++u) {
                float part = fmaf(xq4.x, vv[u].x, fmaf(xq4.y, vv[u].y, fmaf(xq4.z, vv[u].z, xq4.w * vv[u].w)));
                part += __shfl_xor(part, 1);
                part += __shfl_xor(part, 2);
                part += __shfl_xor(part, 4);
                part += __shfl_xor(part, 8);
                if (val[u] && ch == 0) {
                    float d2 = fmaxf(xn + Xn[pp[u]] - 2.f * part, 0.f);
                    keys[ri[u]] = ((u64)__float_as_uint(d2) << 32) | pp[u];
                }
            }
        }
    }
    __syncthreads();

    if (mr <= 512) {
        if (w == 0) {
            u64 rk[8];
#pragma unroll
            for (int i = 0; i < 8; ++i) {
                int idx = lane + (i << 6);
                rk[i] = (idx < mr) ? keys[idx] : ~0ull;
            }
            for (int r = 0; r < KNN; ++r) {
                u64 bk = ~0ull;
                int bs = 0;
#pragma unroll
                for (int i = 0; i < 8; ++i)
                    if (rk[i] < bk) { bk = rk[i]; bs = i; }
                int bo = lane;
#pragma unroll
                for (int off = 1; off < 64; off <<= 1) {
                    u64 ok = __shfl_xor(bk, off);
                    int oo = __shfl_xor(bo, off);
                    if (ok < bk) { bk = ok; bo = oo; }
                }
                if (lane == bo) rk[bs] = ~0ull;
                if (lane == 0) sel[r] = (u32)bk;
            }
        }
        __syncthreads();
    } else {
        for (int r = 0; r < KNN; ++r) {
            u64 bk = ~0ull;
            int bp = -1;
            for (int i = t; i < mr; i += 256) {
                u64 k = keys[i];
                if (k < bk) { bk = k; bp = i; }
            }
#pragma unroll
            for (int off = 32; off > 0; off >>= 1) {
                u64 ok = __shfl_down(bk, off);
                int op = __shfl_down(bp, off);
                if (ok < bk) { bk = ok; bp = op; }
            }
            if (lane == 0) { wk[w] = bk; wp[w] = bp; }
            __syncthreads();
            if (t == 0) {
                u64 fb = wk[0];
                int fp = wp[0];
                for (int v = 1; v < 4; ++v)
                    if (wk[v] < fb) { fb = wk[v]; fp = wp[v]; }
                sel[r] = (u32)(fb & 0xffffffffu);
                if (fp >= 0) keys[fp] = ~0ull;
            }
            __syncthreads();
        }
    }

    int c = t & 15, kk = t >> 4;
#pragma unroll
    for (int rep = 0; rep < 2; ++rep) {
        int k = kk + 16 * rep;
        int nb = min((int)sel[k], N - 1);
        const float* Xr = X + (size_t)nb * FDIM;
        float acc = bg[c];
#pragma unroll
        for (int f = 0; f < FDIM; ++f) acc = fmaf(Xr[f], Wg[f * 16 + c], acc);
        acc = fmaf(y[nb], Wg[FDIM * 16 + c], acc);
        gkc[k * 16 + c] = tanhf(acc);
    }
    __syncthreads();
    if (t < 16) {
        float s = 0.f;
#pragma unroll
        for (int k = 0; k < KNN; ++k) s += gkc[k * 16 + t];
        aggc[t] = s;
    }
    __syncthreads();
    if (t < 128) {
        const float* xq = x + (size_t)q * FDIM;
        float acc = b1[t];
#pragma unroll
        for (int f = 0; f < FDIM; ++f) acc = fmaf(xq[f], W1[f * 128 + t], acc);
#pragma unroll
        for (int cc2 = 0; cc2 < 16; ++cc2) acc = fmaf(aggc[cc2], W1[(FDIM + cc2) * 128 + t], acc);
        red[t] = tanhf(acc) * Wl[t];
    }
    __syncthreads();
    for (int off = 64; off > 0; off >>= 1) {
        if (t < off) red[t] += red[t + off];
        __syncthreads();
    }
    if (t == 0) out[q] = 1.f / (1.f + expf(-(red[0] + bl[0])));
}

extern "C" void kernel_launch(void* const* d_in, const int* in_sizes, int n_in,
                              void* d_out, int out_size, void* d_ws, size_t ws_size,
                              hipStream_t stream) {
    const float* x  = (const float*)d_in[0];
    const float* X  = (const float*)d_in[1];
    const float* y  = (const float*)d_in[2];
    const float* Wg = (const float*)d_in[3];
    const float* bg = (const float*)d_in[4];
    const float* W1 = (const float*)d_in[5];
    const float* b1 = (const float*)d_in[6];
    const float* Wl = (const float*)d_in[7];
    const float* bl = (const float*)d_in[8];
    float* out = (float*)d_out;

    int B = in_sizes[0] / FDIM;  // 1024
    int N = in_sizes[1] / FDIM;  // 200000

    const int strip = 4;
    int nTiles = (N + 127) / 128;
    int nStrips = (nTiles + strip - 1) / strip;
    nStrips = (nStrips + 7) & ~7;
    int nStripsPad = nStrips;           // 392
    int Npad = nStrips * strip * 128;   // 200704

    char* w = (char*)d_ws;
    size_t off = 0;
    auto alloc = [&](size_t bytes) { void* p = w + off; off += (bytes + 255) & ~(size_t)255; return p; };
    float* Xn  = (float*)alloc((size_t)Npad * 4);
    float* qn  = (float*)alloc((size_t)B * 4);
    u32* hist  = (u32*)alloc((size_t)B * 512);
    float* Tq  = (float*)alloc((size_t)B * 4);
    u32* cnt   = (u32*)alloc((size_t)B * 4);

    size_t xTB = (size_t)B * 128;
    size_t XTB = (size_t)(Npad / 16) * 2048;
    size_t segCntB = (size_t)B * nStripsPad * 4;
    size_t segListB = (size_t)B * nStripsPad * SEG * 4;
    size_t ocntB = (size_t)B * 4;
    size_t olistB = (size_t)B * OCAP * 4;
    size_t rem = (ws_size > off) ? ws_size - off : 0;
    bool mfma_path = rem >= xTB + XTB + segCntB + segListB + ocntB + olistB + 4096;

    uint4* xT = nullptr; uint4* XT = nullptr;
    u32 *cnt_seg = nullptr, *list_seg = nullptr, *ocnt = nullptr, *olist = nullptr;
    u32* list_flat = nullptr; unsigned char* d2s = nullptr;
    int cap_flat = 64, Stiles = 0;
    if (mfma_path) {
        xT = (uint4*)alloc(xTB);
        XT = (uint4*)alloc(XTB);
        cnt_seg  = (u32*)alloc(segCntB);
        list_seg = (u32*)alloc(segListB);
        ocnt     = (u32*)alloc(ocntB);
        olist    = (u32*)alloc(olistB);
        rem = (ws_size > off) ? ws_size - off : 0;
        size_t st = rem / ((size_t)B * 128);
        Stiles = st > 100 ? 100 : (int)st;
        int maxFull = N / 128;
        if (Stiles > maxFull) Stiles = maxFull;
        if (Stiles >= 96) d2s = (unsigned char*)alloc((size_t)Stiles * 128 * B);
        else Stiles = 0;
    } else {
        size_t c = rem / ((size_t)B * 4);
        cap_flat = c > MAXCAP ? MAXCAP : (int)c;
        if (cap_flat < 64) cap_flat = 64;
        list_flat = (u32*)alloc((size_t)B * cap_flat * 4);
    }

    if (mfma_path && Stiles > 0 && (B % 32) == 0 && (N % 32) == 0) {
        // fused path: one cvt launch covers x, X, and all padding; ocnt zeroed in thresh2.
        int xBlocks = B / 32;            // 32
        int XPadBlocks = Npad / 32;      // 6272
        k_cvtT_norm2<<<dim3(xBlocks + XPadBlocks), 256, 0, stream>>>(
            x, X, xT, XT, qn, Xn, xBlocks, B, N);

        int S = Stiles * 128;
        k_sample_d2<<<dim3(8, Stiles), 256, 0, stream>>>(xT, XT, qn, Xn, d2s, S);
        k_thresh2<<<dim3(B), 256, 0, stream>>>(d2s, Tq, ocnt, S);

        k_mfma_filter<<<dim3(8 * nStrips), 256, 0, stream>>>(
            xT, XT, qn, Xn, Tq, cnt_seg, list_seg, ocnt, olist, N, nStripsPad, strip, B);

        k_final<<<dim3(B), 256, 0, stream>>>(x, X, y, Xn, Wg, bg, W1, b1, Wl, bl,
                                             cnt_seg, list_seg, ocnt, olist,
                                             nullptr, nullptr, out, nStripsPad, 0, 0, N, B);
    } else if (mfma_path) {
        hipMemsetAsync(Xn + N, 0, (size_t)(Npad - N) * 4, stream);
        size_t realXT = (size_t)(N / 16) * 2048;
        hipMemsetAsync((char*)XT + realXT, 0, XTB - realXT, stream);

        int nxu4 = B * 8, nXu4 = N * 8;
        if ((nxu4 & 255) == 0) {
            k_cvtT_norm<<<dim3(nxu4 / 256), 256, 0, stream>>>(x, xT, qn, nxu4);
        } else {
            k_xnorm<<<dim3((B + 255) / 256), 256, 0, stream>>>(x, qn, B);
            k_cvtT<<<dim3((nxu4 + 255) / 256), 256, 0, stream>>>(x, xT, nxu4);
        }
        if ((nXu4 & 255) == 0) {
            k_cvtT_norm<<<dim3(nXu4 / 256), 256, 0, stream>>>(X, XT, Xn, nXu4);
        } else {
            k_xnorm<<<dim3((N + 255) / 256), 256, 0, stream>>>(X, Xn, N);
            k_cvtT<<<dim3((nXu4 + 255) / 256), 256, 0, stream>>>(X, XT, nXu4);
        }

        if (Stiles > 0) {
            int S = Stiles * 128;
            k_sample_d2<<<dim3(8, Stiles), 256, 0, stream>>>(xT, XT, qn, Xn, d2s, S);
            k_thresh2<<<dim3(B), 256, 0, stream>>>(d2s, Tq, ocnt, S);
        } else {
            hipMemsetAsync(ocnt, 0, ocntB, stream);
            hipMemsetAsync(hist, 0, (size_t)B * 512, stream);
            int nsamp = (N + 15) / 16;
            int chunks = 128;
            int sj = (nsamp + chunks - 1) / chunks;
            k_hist<<<dim3(B / 256, chunks), 256, 0, stream>>>(x, X, Xn, hist, N, nsamp, sj);
            k_thresh<<<dim3((B + 255) / 256), 256, 0, stream>>>(hist, Tq, B);
        }

        k_mfma_filter<<<dim3(8 * nStrips), 256, 0, stream>>>(
            xT, XT, qn, Xn, Tq, cnt_seg, list_seg, ocnt, olist, N, nStripsPad, strip, B);

        k_final<<<dim3(B), 256, 0, stream>>>(x, X, y, Xn, Wg, bg, W1, b1, Wl, bl,
                                             cnt_seg, list_seg, ocnt, olist,
                                             nullptr, nullptr, out, nStripsPad, 0, 0, N, B);
    } else {
        k_xnorm<<<dim3((N + 255) / 256), 256, 0, stream>>>(X, Xn, N);
        k_xnorm<<<dim3((B + 255) / 256), 256, 0, stream>>>(x, qn, B);
        hipMemsetAsync(cnt, 0, (size_t)B * 4, stream);
        hipMemsetAsync(hist, 0, (size_t)B * 512, stream);
        int nsamp = (N + 15) / 16;
        int chunks = 128;
        int sj = (nsamp + chunks - 1) / chunks;
        k_hist<<<dim3(B / 256, chunks), 256, 0, stream>>>(x, X, Xn, hist, N, nsamp, sj);
        k_thresh<<<dim3((B + 255) / 256), 256, 0, stream>>>(hist, Tq, B);
        k_filter_scalar<<<dim3(B / 256, (N + 1023) / 1024), 256, 0, stream>>>(
            x, X, Xn, Tq, cnt, list_flat, N, cap_flat);
        k_final<<<dim3(B), 256, 0, stream>>>(x, X, y, Xn, Wg, bg, W1, b1, Wl, bl,
                                             nullptr, nullptr, nullptr, nullptr,
                                             cnt, list_flat, out, nStripsPad, cap_flat, 1, N, B);
    }
}